// Round 6
// baseline (2285.875 us; speedup 1.0000x reference)
//
#include <hip/hip_runtime.h>
#include <hip/hip_bf16.h>

typedef __hip_bfloat16 bf16;
typedef _Float16 f16;

#define HW 32400
#define NCLS 10
#define PQ 200
#define HIDDEN 128
#define NSPLIT 45
#define SPLITLEN 720    // 45*720 = 32400 exactly
#define CHK 32
#define CAP 6144
#define NBIN 4096
#define L2E 1.44269504f

typedef __attribute__((ext_vector_type(8))) _Float16 half8;
typedef __attribute__((ext_vector_type(8))) short short8;
typedef __attribute__((ext_vector_type(4))) short short4v;
typedef __attribute__((ext_vector_type(4))) float f32x4;

__device__ __forceinline__ float b2f(bf16 v) { return __bfloat162float(v); }
__device__ __forceinline__ void stf(float* p, float v) { *p = v; }
__device__ __forceinline__ void stf(bf16* p, float v) { *p = __float2bfloat16(v); }
// runtime-dtype load: isbf!=0 -> bf16 array, else fp32 array
__device__ __forceinline__ float ldsel(const void* p, long i, unsigned isbf) {
  return isbf ? __bfloat162float(((const bf16*)p)[i]) : ((const float*)p)[i];
}
__device__ __forceinline__ float ldf(const float* p, long i) { return p[i]; }
__device__ __forceinline__ float ldf(const bf16* p, long i) { return __bfloat162float(p[i]); }
__device__ __forceinline__ short f2bf_bits(float v) {
  union { bf16 h; short s; } u; u.h = __float2bfloat16(v); return u.s;
}
__device__ __forceinline__ short f2h_bits(float v) {
  union { f16 h; short s; } u; u.h = (f16)v; return u.s;
}

// ---------------------------------------------------------------------------
// dtype detection (bf16 vs fp32 inputs) -> FLAGS[0]
// ---------------------------------------------------------------------------
__global__ void detect_k(const unsigned* __restrict__ L, unsigned* __restrict__ FLAGS)
{
  __shared__ unsigned cnt[2];
  int tid = threadIdx.x;
  if (tid < 2) cnt[tid] = 0;
  __syncthreads();
  unsigned nz = 0, pl = 0;
  for (int w = tid; w < 4096; w += 256) {
    unsigned u = L[w];
    if (u) {
      nz++;
      unsigned e = (u >> 7) & 0xFF;
      if (e >= 110 && e <= 140) pl++;
    }
  }
  atomicAdd(&cnt[0], nz);
  atomicAdd(&cnt[1], pl);
  __syncthreads();
  if (tid == 0) {
    FLAGS[0] = (2u * cnt[1] > cnt[0]) ? 1u : 0u;
    FLAGS[1] = 0u;
  }
}

// batched weight conversion into fp32 arena (exact in both modes)
struct CvtArgs { const void* src[40]; int n[40]; int off[40]; };
__global__ __launch_bounds__(256) void cvt_k(CvtArgs a, float* __restrict__ dst,
                                             const unsigned* __restrict__ FLAGS)
{
  int j = blockIdx.y;
  unsigned isbf = FLAGS[0];
  int n = a.n[j];
  const void* s = a.src[j];
  float* d = dst + a.off[j];
  for (int t = blockIdx.x * 256 + threadIdx.x; t < n; t += gridDim.x * 256)
    d[t] = ldsel(s, t, isbf);
}

// ---------------------------------------------------------------------------
// Conv weight pre-swizzle into MFMA fragment order (16-bit planes).
// WB[plane][tap][kb][nt][n16][k32] ; value = W[nt*16+n16][kb*32+k][ty][tx]
// dynmode=1 and FLAGS[0]=1 (bf16 inputs): plane0 = bf16 bits (exact), plane1=0.
// else: plane0 = fp16 hi, plane1 = fp16((v - hi) * 4096)  (fp32-split).
// ---------------------------------------------------------------------------
__global__ __launch_bounds__(256) void wprep_k(const float* __restrict__ Wsrc,
    short* __restrict__ WB, int N, int K, int KB, int NTG, int split,
    const unsigned* __restrict__ FLAGS, int dynmode)
{
  unsigned isbf = dynmode ? FLAGS[0] : 0u;
  long total = (long)(split ? 2 : 1) * 9 * KB * NTG * 512;
  for (long t = (long)blockIdx.x * 256 + threadIdx.x; t < total;
       t += (long)gridDim.x * 256) {
    long r = t;
    int k = (int)(r & 31); r >>= 5;
    int n16 = (int)(r & 15); r >>= 4;
    int nt = (int)(r % NTG); r /= NTG;
    int kb = (int)(r % KB); r /= KB;
    int tap = (int)(r % 9); r /= 9;
    int plane = (int)r;
    int n = nt * 16 + n16, kk = kb * 32 + k;
    float v = 0.f;
    if (n < N && kk < K) v = Wsrc[((long)n * K + kk) * 9 + tap];
    short outv;
    if (isbf) {
      outv = (plane == 0) ? f2bf_bits(v) : (short)0;
    } else {
      f16 h = (f16)v;
      if (plane == 0) outv = f2h_bits((float)h);
      else outv = f2h_bits((v - (float)h) * 4096.0f);
    }
    WB[t] = outv;
  }
}

// ---------------------------------------------------------------------------
// MFMA conv2d 3x3 SAME as 9 shifted GEMMs over CW-pixel row chunks.
// MODE 3: fp32-accurate fp16 split (3 MFMAs).  MODE 0: plain fp16.
// MODE 1: exact bf16 (inputs/weights are bf16 -> single bf16 MFMA, exact).
// gate: -1 always run; 0/1 run only when FLAGS[0] matches (dual-launch).
// R15: BATCHED STAGING. The old `for u += 256` runtime-bound staging loop
// serialized 3-4 {8 loads -> wait -> cvt -> ds_write} round-trips per kb
// (up to 4x global latency, nothing to hide it at 2 blocks/CU). Now fully
// unrolled: issue ALL loads into temporaries, one wait, convert+write all.
// Temporaries die before the MFMA phase (unlike R13's carry-across-MFMA,
// which hit 160 VGPR / 10% occupancy). Grid-limited, so VGPR ~110 is free.
// Geometry stays the proven R2 config (CW=60, MT=4, 544 blocks).
// Math order per output unchanged (bit-identical results).
// ---------------------------------------------------------------------------
template <int MODE, int WM, int WN, int MT, int NT, int CW, typename CT>
__global__ __launch_bounds__(256) void conv_mfma(
    const void* __restrict__ A, const unsigned* __restrict__ FLAGS, int dyn,
    int gate, long abatch,
    const short* __restrict__ WB, const float* __restrict__ bias,
    const float* __restrict__ g, const float* __restrict__ beta, int act,
    CT* __restrict__ C, long cbatch, int N, int K, int KB, int NTG)
{
  constexpr int CPR = 180 / CW;              // chunks per row
  constexpr int TOT = 180 * CPR;             // total chunks
  constexpr int BAND = (TOT + 7) / 8;        // chunks per XCD band
  constexpr int PXS = WM * MT * 16 + 2;      // staged px per row (+2 halo)
  constexpr int AW = 3 * PXS * 40;           // [ty][px][k] k-stride 40 (shorts)
  constexpr int UTOT = 3 * PXS * 4;          // staging quanta (short8 each)
  constexpr int NU = (UTOT + 255) / 256;     // per-thread staging quanta
  __shared__ __align__(16) short Ah[AW];
  __shared__ __align__(16) short Al[MODE == 3 ? AW : 8];
  if (gate >= 0 && FLAGS[0] != (unsigned)gate) return;
  // XCD band swizzle: idx = (g&7)*BAND + (g>>3)
  int gsw = blockIdx.x;
  int idx = (gsw & 7) * BAND + (gsw >> 3);
  if (idx >= TOT) return;
  unsigned isbf = dyn ? FLAGS[0] : 0u;
  int bz = blockIdx.z;
  int y = idx / CPR;
  int x0 = (idx % CPR) * CW;
  int tid = threadIdx.x;
  int w = tid >> 6, lane = tid & 63;
  int lane15 = lane & 15, lgrp = lane >> 4;
  int wm = w % WM, wn = w / WM;
  int mbase = wm * MT * 16;
  int nbase = wn * NT * 16;
  f32x4 accM[MT][NT] = {};
  f32x4 accC[MODE == 3 ? MT : 1][MODE == 3 ? NT : 1] = {};
  long planeStride = (long)9 * KB * NTG * 512;

  for (int kb = 0; kb < KB; kb++) {
    __syncthreads();
    // ---- batched staging: issue ALL loads, then one wait, then write ----
    if constexpr (MODE == 1) {
      short8 hv8[NU];
#pragma unroll
      for (int iu = 0; iu < NU; iu++) {
        int u = tid + iu * 256;
        if (u < UTOT) {
          int px = u % PXS;
          int t2 = u / PXS;
          int kg = t2 & 3, row = t2 >> 2;
          int gx = x0 + px - 1, gy = y + row - 1;
          bool in = (gx >= 0 && gx < 180 && gy >= 0 && gy < 180);
          long gbase = (long)bz * abatch + (long)(kb * 32 + kg * 8) * HW +
                       (long)gy * 180 + gx;
          short8 v = {};
          if (in) {
#pragma unroll
            for (int j = 0; j < 8; j++) {
              int kk = kb * 32 + kg * 8 + j;
              v[j] = (kk < K) ? ((const short*)A)[gbase + (long)j * HW]
                              : (short)0;
            }
          }
          hv8[iu] = v;
        }
      }
#pragma unroll
      for (int iu = 0; iu < NU; iu++) {
        int u = tid + iu * 256;
        if (u < UTOT) {
          int px = u % PXS;
          int t2 = u / PXS;
          int kg = t2 & 3, row = t2 >> 2;
          int o = (row * PXS + px) * 40 + kg * 8;
          *(short8*)&Ah[o] = hv8[iu];
        }
      }
    } else {
      float pv[NU][8];
#pragma unroll
      for (int iu = 0; iu < NU; iu++) {
        int u = tid + iu * 256;
        if (u < UTOT) {
          int px = u % PXS;
          int t2 = u / PXS;
          int kg = t2 & 3, row = t2 >> 2;
          int gx = x0 + px - 1, gy = y + row - 1;
          bool in = (gx >= 0 && gx < 180 && gy >= 0 && gy < 180);
          long gbase = (long)bz * abatch + (long)(kb * 32 + kg * 8) * HW +
                       (long)gy * 180 + gx;
#pragma unroll
          for (int j = 0; j < 8; j++) {
            int kk = kb * 32 + kg * 8 + j;
            pv[iu][j] =
                (in && kk < K) ? ldsel(A, gbase + (long)j * HW, isbf) : 0.f;
          }
        }
      }
#pragma unroll
      for (int iu = 0; iu < NU; iu++) {
        int u = tid + iu * 256;
        if (u < UTOT) {
          int px = u % PXS;
          int t2 = u / PXS;
          int kg = t2 & 3, row = t2 >> 2;
          int o = (row * PXS + px) * 40 + kg * 8;
          short8 hv, lv;
#pragma unroll
          for (int j = 0; j < 8; j++) {
            float v = pv[iu][j];
            f16 h = (f16)v;
            hv[j] = f2h_bits((float)h);
            if constexpr (MODE == 3) lv[j] = f2h_bits((v - (float)h) * 4096.0f);
          }
          *(short8*)&Ah[o] = hv;
          if constexpr (MODE == 3) *(short8*)&Al[o] = lv;
        }
      }
    }
    __syncthreads();
#pragma unroll
    for (int tap = 0; tap < 9; tap++) {
      int ty = tap / 3, tx = tap % 3;
      const short* wb = WB + (((long)tap * KB + kb) * NTG) * 512;
      if constexpr (MODE == 1) {
        short8 bh[NT];
#pragma unroll
        for (int nt = 0; nt < NT; nt++) {
          long o = (long)(wn * NT + nt) * 512 + lane15 * 32 + lgrp * 8;
          bh[nt] = *(const short8*)(wb + o);
        }
        short8 ah[MT];
#pragma unroll
        for (int mt = 0; mt < MT; mt++) {
          int px = mbase + mt * 16 + lane15 + tx;
          ah[mt] = *(const short8*)&Ah[(ty * PXS + px) * 40 + lgrp * 8];
        }
#pragma unroll
        for (int mt = 0; mt < MT; mt++)
#pragma unroll
          for (int nt = 0; nt < NT; nt++)
            accM[mt][nt] = __builtin_amdgcn_mfma_f32_16x16x32_bf16(
                ah[mt], bh[nt], accM[mt][nt], 0, 0, 0);
      } else {
        half8 bh[NT], bl[MODE == 3 ? NT : 1];
#pragma unroll
        for (int nt = 0; nt < NT; nt++) {
          long o = (long)(wn * NT + nt) * 512 + lane15 * 32 + lgrp * 8;
          bh[nt] = *(const half8*)(wb + o);
          if constexpr (MODE == 3) bl[nt] = *(const half8*)(wb + planeStride + o);
        }
        half8 ah[MT], al[MODE == 3 ? MT : 1];
#pragma unroll
        for (int mt = 0; mt < MT; mt++) {
          int px = mbase + mt * 16 + lane15 + tx;
          int o = (ty * PXS + px) * 40 + lgrp * 8;
          ah[mt] = *(const half8*)&Ah[o];
          if constexpr (MODE == 3) al[mt] = *(const half8*)&Al[o];
        }
#pragma unroll
        for (int mt = 0; mt < MT; mt++)
#pragma unroll
          for (int nt = 0; nt < NT; nt++) {
            accM[mt][nt] = __builtin_amdgcn_mfma_f32_16x16x32_f16(
                ah[mt], bh[nt], accM[mt][nt], 0, 0, 0);
            if constexpr (MODE == 3) {
              accC[mt][nt] = __builtin_amdgcn_mfma_f32_16x16x32_f16(
                  al[mt], bh[nt], accC[mt][nt], 0, 0, 0);
              accC[mt][nt] = __builtin_amdgcn_mfma_f32_16x16x32_f16(
                  ah[mt], bl[nt], accC[mt][nt], 0, 0, 0);
            }
          }
      }
    }
  }
  int pixbase = y * 180 + x0;
#pragma unroll
  for (int mt = 0; mt < MT; mt++) {
    int m = mbase + mt * 16 + lgrp * 4;
    if (m >= CW) continue;
#pragma unroll
    for (int nt = 0; nt < NT; nt++) {
      int n = nbase + nt * 16 + lane15;
      if (n >= N) continue;
      float bi = bias[n];
      float gg = g ? g[n] : 1.f;
      float bb = g ? beta[n] : 0.f;
      long base = (long)bz * cbatch + (long)n * HW + pixbase + m;
      float vv[4];
#pragma unroll
      for (int r = 0; r < 4; r++) {
        float v = accM[mt][nt][r];
        if constexpr (MODE == 3) v += accC[mt][nt][r] * (1.f / 4096.f);
        v += bi;
        if (g) v = v * gg + bb;
        if (act == 1) v = fmaxf(v, 0.f);
        else if (act == 2) v = 1.f / (1.f + expf(-v));
        vv[r] = v;
      }
      if constexpr (sizeof(CT) == 4) {
        if (m + 3 < CW) {
          f32x4 ov; ov[0] = vv[0]; ov[1] = vv[1]; ov[2] = vv[2]; ov[3] = vv[3];
          *(f32x4*)&C[base] = ov;
        } else {
#pragma unroll
          for (int r = 0; r < 4; r++) if (m + r < CW) C[base + r] = vv[r];
        }
      } else {
        if (m + 3 < CW) {
          short4v ov;
#pragma unroll
          for (int r = 0; r < 4; r++) ov[r] = f2bf_bits(vv[r]);
          *(short4v*)&C[base] = ov;
        } else {
#pragma unroll
          for (int r = 0; r < 4; r++)
            if (m + r < CW) *((short*)&C[base + r]) = f2bf_bits(vv[r]);
        }
      }
    }
  }
}

// ---------------------------------------------------------------------------
// bf16 MFMA KV projection: C = (A1+A2) @ W^T + bias.
// R15: y-merged — each block covers 128 of 256 output rows (NT=4, grid y=2),
// halving A re-reads (4x -> 2x) and block count. Same per-output math order.
// ---------------------------------------------------------------------------
__global__ __launch_bounds__(256) void kvproj_k(
    const bf16* __restrict__ A1, const bf16* __restrict__ A2,
    const float* __restrict__ Wf, const float* __restrict__ bias,
    bf16* __restrict__ C)
{
  __shared__ __align__(16) short As[64 * 40];
  int m0 = blockIdx.x * 64;
  int n0 = blockIdx.y * 128;
  int b = blockIdx.z;
  int tid = threadIdx.x;
  int w = tid >> 6, lane = tid & 63;
  int lane15 = lane & 15, lgrp = lane >> 4;
  int wm = w & 1, wn = w >> 1;
  const bf16* A1b = A1 + (long)b * 128 * HW;
  f32x4 acc[2][4] = {};
  for (int kb = 0; kb < 4; kb++) {
    __syncthreads();
    for (int e = tid; e < 2048; e += 256) {
      int k = e >> 6, m = e & 63;
      int gm = m0 + m;
      float v = 0.f;
      if (gm < HW) {
        long idx = (long)(kb * 32 + k) * HW + gm;
        v = b2f(A1b[idx]) + b2f(A2[idx]);
      }
      As[m * 40 + k] = f2bf_bits(v);
    }
    __syncthreads();
    short8 bh[4];
#pragma unroll
    for (int nt = 0; nt < 4; nt++) {
      int n = n0 + wn * 64 + nt * 16 + lane15;
      const float* wr = Wf + (long)n * 128 + kb * 32 + lgrp * 8;
      float4 w0 = *(const float4*)wr;
      float4 w1 = *(const float4*)(wr + 4);
      short8 t;
      t[0] = f2bf_bits(w0.x); t[1] = f2bf_bits(w0.y);
      t[2] = f2bf_bits(w0.z); t[3] = f2bf_bits(w0.w);
      t[4] = f2bf_bits(w1.x); t[5] = f2bf_bits(w1.y);
      t[6] = f2bf_bits(w1.z); t[7] = f2bf_bits(w1.w);
      bh[nt] = t;
    }
    short8 ah[2];
#pragma unroll
    for (int mt = 0; mt < 2; mt++) {
      int m = wm * 32 + mt * 16 + lane15;
      ah[mt] = *(const short8*)&As[m * 40 + lgrp * 8];
    }
#pragma unroll
    for (int mt = 0; mt < 2; mt++)
#pragma unroll
      for (int nt = 0; nt < 4; nt++)
        acc[mt][nt] = __builtin_amdgcn_mfma_f32_16x16x32_bf16(
            ah[mt], bh[nt], acc[mt][nt], 0, 0, 0);
  }
#pragma unroll
  for (int mt = 0; mt < 2; mt++) {
    int mq = m0 + wm * 32 + mt * 16 + lgrp * 4;
    if (mq >= HW) continue;
#pragma unroll
    for (int nt = 0; nt < 4; nt++) {
      int n = n0 + wn * 64 + nt * 16 + lane15;
      float bi = bias[n];
      short4v ov;
#pragma unroll
      for (int r = 0; r < 4; r++) ov[r] = f2bf_bits(acc[mt][nt][r] + bi);
      *(short4v*)&C[(long)b * 256 * HW + (long)n * HW + mq] = ov;
    }
  }
}

// ---------------------------------------------------------------------------
// bf16 MFMA KPE projection: KPET[n][m] = posembed_relu(m) @ W2^T + b2.
// ---------------------------------------------------------------------------
__global__ __launch_bounds__(256) void kpe_mfma_k(
    const float* __restrict__ pe1w, const float* __restrict__ pe1b,
    const float* __restrict__ pe1g, const float* __restrict__ pe1bt,
    const float* __restrict__ W2, const float* __restrict__ b2,
    bf16* __restrict__ C)
{
  __shared__ __align__(16) short As[64 * 40];
  int m0 = blockIdx.x * 64;
  int n0 = blockIdx.y * 64;
  int tid = threadIdx.x;
  int w = tid >> 6, lane = tid & 63;
  int lane15 = lane & 15, lgrp = lane >> 4;
  int wm = w & 1, wn = w >> 1;
  f32x4 acc[2][2] = {};
  for (int kb = 0; kb < 4; kb++) {
    __syncthreads();
    for (int e = tid; e < 2048; e += 256) {
      int k = e >> 6, m = e & 63;
      int gm = m0 + m;
      int kk = kb * 32 + k;
      float v = 0.f;
      if (gm < HW) {
        float p0 = (float)(gm / 180) + 0.5f;
        float p1 = (float)(gm % 180) + 0.5f;
        float t = p0 * pe1w[kk * 2] + p1 * pe1w[kk * 2 + 1] + pe1b[kk];
        t = t * pe1g[kk] + pe1bt[kk];
        v = fmaxf(t, 0.f);
      }
      As[m * 40 + k] = f2bf_bits(v);
    }
    __syncthreads();
    short8 bh[2];
#pragma unroll
    for (int nt = 0; nt < 2; nt++) {
      int n = n0 + wn * 32 + nt * 16 + lane15;
      const float* wr = W2 + (long)n * 128 + kb * 32 + lgrp * 8;
      float4 w0 = *(const float4*)wr;
      float4 w1 = *(const float4*)(wr + 4);
      short8 t;
      t[0] = f2bf_bits(w0.x); t[1] = f2bf_bits(w0.y);
      t[2] = f2bf_bits(w0.z); t[3] = f2bf_bits(w0.w);
      t[4] = f2bf_bits(w1.x); t[5] = f2bf_bits(w1.y);
      t[6] = f2bf_bits(w1.z); t[7] = f2bf_bits(w1.w);
      bh[nt] = t;
    }
    short8 ah[2];
#pragma unroll
    for (int mt = 0; mt < 2; mt++) {
      int m = wm * 32 + mt * 16 + lane15;
      ah[mt] = *(const short8*)&As[m * 40 + lgrp * 8];
    }
#pragma unroll
    for (int mt = 0; mt < 2; mt++)
#pragma unroll
      for (int nt = 0; nt < 2; nt++)
        acc[mt][nt] = __builtin_amdgcn_mfma_f32_16x16x32_bf16(
            ah[mt], bh[nt], acc[mt][nt], 0, 0, 0);
  }
#pragma unroll
  for (int mt = 0; mt < 2; mt++) {
    int mq = m0 + wm * 32 + mt * 16 + lgrp * 4;
    if (mq >= HW) continue;   // mq 4-aligned, HW%4==0 -> vector store safe
#pragma unroll
    for (int nt = 0; nt < 2; nt++) {
      int n = n0 + wn * 32 + nt * 16 + lane15;
      float bi = b2[n];
      short4v ov;
#pragma unroll
      for (int r = 0; r < 4; r++) ov[r] = f2bf_bits(acc[mt][nt][r] + bi);
      *(short4v*)&C[(long)n * HW + mq] = ov;
    }
  }
}

// ---------------------------------------------------------------------------
// Generic tiled GEMM: C = act((A [+A2]) @ W^T + bias) (+ res)
// amode 0: A[m*lda+k] (+A2 same layout).  amode 3: fused QUERY pos-embed.
// cmode 0: C[m*ldc+n] ; cmode 1: C[n*ldc+m].  K multiple of 16.
// ---------------------------------------------------------------------------
template <typename AT, typename CT>
__global__ __launch_bounds__(256) void gemm_k(
    const AT* __restrict__ A, const AT* __restrict__ A2, int lda, int amode,
    long abatch,
    const float* __restrict__ W, const float* __restrict__ bias, int act,
    const float* __restrict__ res,
    const float* __restrict__ pe1w, const float* __restrict__ pe1b,
    const float* __restrict__ pe1g, const float* __restrict__ pe1bt,
    CT* __restrict__ C, int ldc, int cmode, long cbatch,
    int M, int N, int K)
{
  __shared__ __align__(16) float As[16][68];
  __shared__ __align__(16) float Ws[16][68];
  int b = blockIdx.z;
  int m0 = blockIdx.x * 64, n0 = blockIdx.y * 64;
  int tid = threadIdx.x;
  int nt = tid & 15, mt = tid >> 4;
  float acc[4][4] = {};
  const AT* Ab = A + (long)b * abatch;
  for (int k0 = 0; k0 < K; k0 += 16) {
    if (amode == 0) {
      for (int e = tid; e < 1024; e += 256) {
        int m = e >> 4, k = e & 15;
        float v = 0.f;
        if (m0 + m < M) {
          long idx = (long)(m0 + m) * lda + k0 + k;
          v = ldf(Ab, idx);
          if (A2) v += ldf(A2, idx);
        }
        As[k][m] = v;
      }
    } else { // amode 3: query pos-embed, A = qpos (fp32 [M][2])
      const float* qp = (const float*)A;
      for (int e = tid; e < 1024; e += 256) {
        int m = e & 63, k = e >> 6;
        float v = 0.f;
        int gm = m0 + m;
        if (gm < M) {
          float p0 = qp[gm * 2], p1 = qp[gm * 2 + 1];
          int kk = k0 + k;
          float t = p0 * pe1w[kk * 2] + p1 * pe1w[kk * 2 + 1] + pe1b[kk];
          t = t * pe1g[kk] + pe1bt[kk];
          v = fmaxf(t, 0.f);
        }
        As[k][m] = v;
      }
    }
    for (int e = tid; e < 1024; e += 256) {
      int n = e >> 4, k = e & 15;
      float v = 0.f;
      if (n0 + n < N) v = W[(long)(n0 + n) * K + k0 + k];
      Ws[k][n] = v;
    }
    __syncthreads();
#pragma unroll
    for (int kk = 0; kk < 16; kk++) {
      float4 av = *(const float4*)&As[kk][mt * 4];
      float4 wv = *(const float4*)&Ws[kk][nt * 4];
      float am[4] = {av.x, av.y, av.z, av.w};
      float wn[4] = {wv.x, wv.y, wv.z, wv.w};
#pragma unroll
      for (int mi = 0; mi < 4; mi++)
#pragma unroll
        for (int ni = 0; ni < 4; ni++)
          acc[mi][ni] = fmaf(am[mi], wn[ni], acc[mi][ni]);
    }
    __syncthreads();
  }
#pragma unroll
  for (int mi = 0; mi < 4; mi++) {
    int m = m0 + mt * 4 + mi;
    if (m >= M) continue;
#pragma unroll
    for (int ni = 0; ni < 4; ni++) {
      int n = n0 + nt * 4 + ni;
      if (n >= N) continue;
      float v = acc[mi][ni];
      if (bias) v += bias[n];
      if (act == 1) v = fmaxf(v, 0.f);
      if (res) v += res[(long)m * ldc + n];
      long ci = (cmode == 0) ? ((long)b * cbatch + (long)m * ldc + n)
                             : ((long)b * cbatch + (long)n * ldc + m);
      stf(&C[ci], v);
    }
  }
}

// ---------------------------------------------------------------------------
__global__ void nms_k(const float* __restrict__ HEAT, float* __restrict__ SCORE)
{
  int t = blockIdx.x * 256 + threadIdx.x;
  if (t >= 2 * NCLS * HW) return;
  int b = t / (NCLS * HW); int r = t % (NCLS * HW);
  int cls = r / HW; int n = r % HW;
  const float* hb = HEAT + ((long)(b * NCLS + cls)) * HW;
  float v = hb[n];
  bool keep = true;
  if (cls < 8) {
    int y = n / 180, x = n % 180;
    if (y == 0 || y == 179 || x == 0 || x == 179) keep = false;
    else {
      float mx = -1e30f;
#pragma unroll
      for (int dy = -1; dy <= 1; dy++)
#pragma unroll
        for (int dx = -1; dx <= 1; dx++)
          mx = fmaxf(mx, hb[(y + dy) * 180 + x + dx]);
      keep = (v == mx);
    }
  }
  SCORE[(long)b * (NCLS * HW) + r] = keep ? v : 0.f;
}

__global__ void zero_u32(unsigned* p, int n)
{
  int t = blockIdx.x * 256 + threadIdx.x;
  if (t < n) p[t] = 0;
}

__global__ __launch_bounds__(256) void hist_k(const float* __restrict__ SCORE,
                                              unsigned* __restrict__ HIST)
{
  __shared__ unsigned lh[NBIN];
  int b = blockIdx.y;
  for (int e = threadIdx.x; e < NBIN; e += 256) lh[e] = 0;
  __syncthreads();
  int start = blockIdx.x * 1350;
  const float* sb = SCORE + (long)b * (NCLS * HW);
  for (int e = start + threadIdx.x; e < start + 1350; e += 256) {
    unsigned bits = __float_as_uint(sb[e]);
    atomicAdd(&lh[bits >> 18], 1u);
  }
  __syncthreads();
  for (int e = threadIdx.x; e < NBIN; e += 256) {
    unsigned c = lh[e];
    if (c) atomicAdd(&HIST[b * NBIN + e], c);
  }
}

__global__ void thresh_k(const unsigned* __restrict__ HIST, unsigned* __restrict__ THR)
{
  __shared__ unsigned ps[256];
  int b = blockIdx.x;
  const unsigned* hb = HIST + b * NBIN;
  unsigned s = 0;
  for (int j = 0; j < 16; j++) s += hb[threadIdx.x * 16 + j];
  ps[threadIdx.x] = s;
  __syncthreads();
  if (threadIdx.x == 0) {
    unsigned cum = 0; int t = 255;
    for (; t > 0; t--) { if (cum + ps[t] >= PQ) break; cum += ps[t]; }
    int bin = t * 16 + 15;
    for (; bin > t * 16; bin--) { unsigned c = hb[bin]; if (cum + c >= PQ) break; cum += c; }
    if (bin < 1) bin = 1;
    THR[b] = (unsigned)bin;
  }
}

__global__ void collect_k(const float* __restrict__ SCORE, const unsigned* __restrict__ THR,
                          unsigned* __restrict__ ACNT, unsigned long long* __restrict__ CAND)
{
  int t = blockIdx.x * 256 + threadIdx.x;
  if (t >= 2 * NCLS * HW) return;
  int b = t / (NCLS * HW); int r = t % (NCLS * HW);
  float v = SCORE[(long)b * (NCLS * HW) + r];
  unsigned bits = __float_as_uint(v);
  if ((bits >> 18) >= THR[b]) {
    unsigned slot = atomicAdd(&ACNT[b], 1u);
    if (slot < CAP) CAND[(long)b * CAP + slot] =
        ((unsigned long long)bits << 32) | (unsigned)(~r);
  }
}

__global__ __launch_bounds__(64) void select_k(
    const unsigned long long* __restrict__ CAND, const unsigned* __restrict__ ACNT,
    unsigned* __restrict__ TOPC, unsigned* __restrict__ TOPI, float* __restrict__ QPA)
{
  __shared__ unsigned long long cnd[CAP];
  int b = blockIdx.x;
  int lane = threadIdx.x;
  unsigned cnt = ACNT[b]; if (cnt > CAP) cnt = CAP;
  for (int e = lane; e < (int)cnt; e += 64) cnd[e] = CAND[(long)b * CAP + e];
  __syncthreads();
  for (int p = 0; p < PQ; p++) {
    unsigned long long best = 0;
    for (int e = lane; e < (int)cnt; e += 64) { unsigned long long c = cnd[e]; if (c > best) best = c; }
#pragma unroll
    for (int o = 32; o; o >>= 1) {
      unsigned long long other = __shfl_xor(best, o, 64);
      if (other > best) best = other;
    }
    for (int e = lane; e < (int)cnt; e += 64) if (best != 0 && cnd[e] == best) cnd[e] = 0;
    if (lane == 0) {
      unsigned idx = (best == 0) ? 0u : ~(unsigned)(best & 0xFFFFFFFFull);
      if (idx >= NCLS * HW) idx = 0;
      unsigned cls = idx / HW, n = idx % HW;
      TOPC[b * PQ + p] = cls; TOPI[b * PQ + p] = n;
      QPA[((long)(b * PQ + p)) * 2 + 0] = (float)(n / 180) + 0.5f;
      QPA[((long)(b * PQ + p)) * 2 + 1] = (float)(n % 180) + 0.5f;
    }
    __syncthreads();
  }
}

__global__ void gather_k(const float* __restrict__ LIDF, const unsigned* __restrict__ TOPC,
                         const unsigned* __restrict__ TOPI, const float* __restrict__ cew,
                         const float* __restrict__ ceb, float* __restrict__ X)
{
  int t = blockIdx.x * 256 + threadIdx.x;
  if (t >= 2 * PQ * HIDDEN) return;
  int c = t & 127; int r = t >> 7; int p = r % PQ; int b = r / PQ;
  unsigned n = TOPI[b * PQ + p]; unsigned cls = TOPC[b * PQ + p];
  if (n >= HW) n = 0;
  if (cls >= NCLS) cls = 0;
  X[t] = LIDF[((long)(b * HIDDEN + c)) * HW + n] + cew[c * NCLS + cls] + ceb[c];
}

__global__ __launch_bounds__(64) void self_attn_k(const float* __restrict__ SQKV,
                                                  float* __restrict__ SAO)
{
  int q = blockIdx.x, h = blockIdx.y, b = blockIdx.z;
  int lane = threadIdx.x;
  const float* qp = SQKV + ((long)(b * PQ + q)) * 384 + h * 16;
  float qv[16];
#pragma unroll
  for (int d = 0; d < 16; d++) qv[d] = qp[d] * 0.25f;
  float sv[4]; int kks[4]; int nk = 0;
  float lmax = -1e30f;
  for (int kk = lane; kk < PQ; kk += 64) {
    const float* kp = SQKV + ((long)(b * PQ + kk)) * 384 + 128 + h * 16;
    float s = 0.f;
#pragma unroll
    for (int d = 0; d < 16; d++) s = fmaf(qv[d], kp[d], s);
    sv[nk] = s; kks[nk] = kk; nk++;
    lmax = fmaxf(lmax, s);
  }
#pragma unroll
  for (int o = 32; o; o >>= 1) lmax = fmaxf(lmax, __shfl_xor(lmax, o, 64));
  float lsum = 0.f; float acc[16] = {};
  for (int t = 0; t < nk; t++) {
    float p = expf(sv[t] - lmax);
    lsum += p;
    const float* vp = SQKV + ((long)(b * PQ + kks[t])) * 384 + 256 + h * 16;
#pragma unroll
    for (int d = 0; d < 16; d++) acc[d] = fmaf(p, vp[d], acc[d]);
  }
#pragma unroll
  for (int o = 32; o; o >>= 1) lsum += __shfl_xor(lsum, o, 64);
#pragma unroll
  for (int d = 0; d < 16; d++) {
    float v = acc[d];
#pragma unroll
    for (int o = 32; o; o >>= 1) v += __shfl_xor(v, o, 64);
    if (lane == 0) SAO[((long)(b * PQ + q)) * HIDDEN + h * 16 + d] = v / lsum;
  }
}

// ---------------------------------------------------------------------------
// MFMA flash cross-attention, key-split (R11 structure kept).
// ---------------------------------------------------------------------------
__global__ __launch_bounds__(256) void flash_mfma_k(const float* __restrict__ QH,
                                                    const bf16* __restrict__ KVT,
                                                    float* __restrict__ PART)
{
  __shared__ __align__(16) short Qs[64 * 40];      // [q][d] d in [16,32) zero
  __shared__ __align__(16) short Ks[2][32 * 40];   // [key][d] d in [16,32) zero
  __shared__ __align__(16) short Vs[2][16 * 40];   // [d][key]
  __shared__ __align__(16) short Ps[4][16 * 40];   // per-wave [q][key]
  int s = blockIdx.x, h = blockIdx.y;
  int b = blockIdx.z >> 2, qb = blockIdx.z & 3;
  int tid = threadIdx.x;
  int w = tid >> 6, lane = tid & 63;
  int lane15 = lane & 15, lgrp = lane >> 4;
  const short* Kb = (const short*)KVT + ((long)b * 256 + h * 16) * HW;
  const short* Vb = Kb + (long)128 * HW;
  int nbeg = s * SPLITLEN;

  // zero the d=[16,32) pad of both K buffers (disjoint from staged d<16)
  for (int e = tid; e < 2 * 32 * 16; e += 256) {
    int buf = e >> 9, rr = e & 511;
    int kk = rr >> 4, d2 = rr & 15;
    Ks[buf][kk * 40 + 16 + d2] = 0;
  }
  // stage Q once: q = tid>>2 (0..63), dgroup = tid&3 -> short8 at [q][dg*8]
  {
    int q = tid >> 2, dg = tid & 3;
    int gq = qb * 64 + q;
    short8 v = {};
    if (dg < 2 && gq < PQ) {
      const float* qp = QH + ((long)(b * PQ + gq)) * HIDDEN + h * 16 + dg * 8;
#pragma unroll
      for (int j = 0; j < 8; j++) v[j] = f2bf_bits(qp[j] * 0.25f);
    }
    *(short8*)&Qs[q * 40 + dg * 8] = v;
  }

  auto stageKV = [&](int t, int buf) {
    int kb0 = nbeg + t * CHK;
    for (int e = tid; e < 512; e += 256) {
      int d = e >> 5, kk = e & 31;
      long gk = kb0 + kk; if (gk >= HW) gk = HW - 1;   // clamped; masked later
      long go = (long)d * HW + gk;
      Ks[buf][kk * 40 + d] = Kb[go];
      Vs[buf][d * 40 + kk] = Vb[go];
    }
  };

  stageKV(0, 0);
  __syncthreads();

  short8 aq = *(const short8*)&Qs[(w * 16 + lane15) * 40 + lgrp * 8];
  float m[4] = {-1e30f, -1e30f, -1e30f, -1e30f};
  float l[4] = {0.f, 0.f, 0.f, 0.f};
  f32x4 accO = {};
  const int NTL = (SPLITLEN + CHK - 1) / CHK;  // 23 (last chunk 16 valid)
  for (int t = 0; t < NTL; t++) {
    int cur = t & 1;
    if (t + 1 < NTL) stageKV(t + 1, cur ^ 1);
    int valid = SPLITLEN - t * CHK; if (valid > CHK) valid = CHK;
    short8 bk0 = *(const short8*)&Ks[cur][lane15 * 40 + lgrp * 8];
    short8 bk1 = *(const short8*)&Ks[cur][(16 + lane15) * 40 + lgrp * 8];
    f32x4 z = {};
    f32x4 s0 = __builtin_amdgcn_mfma_f32_16x16x32_bf16(aq, bk0, z, 0, 0, 0);
    f32x4 s1 = __builtin_amdgcn_mfma_f32_16x16x32_bf16(aq, bk1, z, 0, 0, 0);
    bool msk0 = (lane15 >= valid);
    bool msk1 = (16 + lane15 >= valid);
#pragma unroll
    for (int r = 0; r < 4; r++) {
      float x0 = msk0 ? -1e30f : s0[r];
      float x1 = msk1 ? -1e30f : s1[r];
      float mx = fmaxf(x0, x1);
      mx = fmaxf(mx, __shfl_xor(mx, 1, 64));
      mx = fmaxf(mx, __shfl_xor(mx, 2, 64));
      mx = fmaxf(mx, __shfl_xor(mx, 4, 64));
      mx = fmaxf(mx, __shfl_xor(mx, 8, 64));
      float mn = fmaxf(m[r], mx);
      float p0 = exp2f((x0 - mn) * L2E);
      float p1 = exp2f((x1 - mn) * L2E);
      float sum = p0 + p1;
      sum += __shfl_xor(sum, 1, 64);
      sum += __shfl_xor(sum, 2, 64);
      sum += __shfl_xor(sum, 4, 64);
      sum += __shfl_xor(sum, 8, 64);
      float al = exp2f((m[r] - mn) * L2E);
      l[r] = l[r] * al + sum;
      m[r] = mn;
      accO[r] *= al;
      Ps[w][(lgrp * 4 + r) * 40 + lane15] = f2bf_bits(p0);
      Ps[w][(lgrp * 4 + r) * 40 + 16 + lane15] = f2bf_bits(p1);
    }
    short8 ap = *(const short8*)&Ps[w][lane15 * 40 + lgrp * 8];
    short8 bv = *(const short8*)&Vs[cur][lane15 * 40 + lgrp * 8];
    accO = __builtin_amdgcn_mfma_f32_16x16x32_bf16(ap, bv, accO, 0, 0, 0);
    __syncthreads();
  }
  long base = ((((long)(b * 8 + h)) * NSPLIT + s) * PQ) * 18;
#pragma unroll
  for (int r = 0; r < 4; r++) {
    int gq = qb * 64 + w * 16 + lgrp * 4 + r;
    if (gq < PQ) {
      long ro = base + (long)gq * 18;
      PART[ro + lane15] = accO[r];
      if (lane15 == 0) { PART[ro + 16] = m[r]; PART[ro + 17] = l[r]; }
    }
  }
}

__global__ void combine_k(const float* __restrict__ PART, float* __restrict__ CAO)
{
  int t = blockIdx.x * 256 + threadIdx.x;
  if (t >= 2 * 8 * PQ * 16) return;
  int d = t & 15; int r = t >> 4;
  int q = r % PQ; r /= PQ;
  int h = r & 7; int b = r >> 3;
  long base = (((long)(b * 8 + h)) * NSPLIT) * PQ * 18 + (long)q * 18;
  float M = -1e30f;
  for (int s = 0; s < NSPLIT; s++) M = fmaxf(M, PART[base + (long)s * PQ * 18 + 16]);
  float L = 0.f, O = 0.f;
  for (int s = 0; s < NSPLIT; s++) {
    long p0 = base + (long)s * PQ * 18;
    float w = expf(PART[p0 + 16] - M);
    L += PART[p0 + 17] * w;
    O += PART[p0 + d] * w;
  }
  CAO[((long)(b * PQ + q)) * HIDDEN + h * 16 + d] = (L > 0.f) ? O / L : 0.f;
}

__global__ __launch_bounds__(256) void ln_k(const float* __restrict__ PRE,
                                            const float* __restrict__ g,
                                            const float* __restrict__ bta,
                                            float* __restrict__ X)
{
  int row = blockIdx.x * 4 + (threadIdx.x >> 6);
  int lane = threadIdx.x & 63;
  const float* p = PRE + (long)row * HIDDEN;
  float v0 = p[lane], v1 = p[lane + 64];
  float s = v0 + v1;
#pragma unroll
  for (int o = 32; o; o >>= 1) s += __shfl_xor(s, o, 64);
  float mu = s * (1.f / 128.f);
  float d0 = v0 - mu, d1 = v1 - mu;
  float vs = d0 * d0 + d1 * d1;
#pragma unroll
  for (int o = 32; o; o >>= 1) vs += __shfl_xor(vs, o, 64);
  float rs = rsqrtf(vs * (1.f / 128.f) + 1e-5f);
  float* xo = X + (long)row * HIDDEN;
  xo[lane] = d0 * rs * g[lane] + bta[lane];
  xo[lane + 64] = d1 * rs * g[lane + 64] + bta[lane + 64];
}

__global__ __launch_bounds__(128) void conv1d_k(const float* __restrict__ X,
                                                const float* __restrict__ w,
                                                const float* __restrict__ bias,
                                                const float* __restrict__ g,
                                                const float* __restrict__ beta,
                                                float* __restrict__ Y)
{
  int p = blockIdx.x, b = blockIdx.y;
  int co = threadIdx.x;
  __shared__ float xs[3][HIDDEN];
  for (int e = co; e < 3 * HIDDEN; e += HIDDEN) {
    int t = e >> 7, c = e & 127;
    int pp = p + t - 1;
    xs[t][c] = (pp >= 0 && pp < PQ) ? X[((long)(b * PQ + pp)) * HIDDEN + c] : 0.f;
  }
  __syncthreads();
  const float* wr = w + (long)co * HIDDEN * 3;
  float acc = 0.f;
  for (int c = 0; c < HIDDEN; c++) {
    acc = fmaf(xs[0][c], wr[c * 3 + 0], acc);
    acc = fmaf(xs[1][c], wr[c * 3 + 1], acc);
    acc = fmaf(xs[2][c], wr[c * 3 + 2], acc);
  }
  float v = (acc + bias[co]) * g[co] + beta[co];
  Y[((long)(b * PQ + p)) * HIDDEN + co] = fmaxf(v, 0.f);
}

__global__ void head2_k(const float* __restrict__ Y, const float* __restrict__ w,
                        const float* __restrict__ bias, const float* __restrict__ qpos,
                        float* __restrict__ OUT, int N, float* __restrict__ qnext)
{
  int t = blockIdx.x * 256 + threadIdx.x;
  if (t >= 2 * N * PQ) return;
  int p = t % PQ; int r = t / PQ; int co = r % N; int b = r / N;
  const float* wr = w + (long)co * HIDDEN * 3;
  float acc = 0.f;
  for (int tap = 0; tap < 3; tap++) {
    int pp = p + tap - 1;
    if (pp < 0 || pp >= PQ) continue;
    const float* yr = Y + ((long)(b * PQ + pp)) * HIDDEN;
    for (int c = 0; c < HIDDEN; c++)
      acc = fmaf(yr[c], wr[c * 3 + tap], acc);
  }
  float v = acc + bias[co];
  if (qpos) v += qpos[((long)(b * PQ + p)) * 2 + co];
  OUT[((long)(b * N + co)) * PQ + p] = v;
  if (qnext) qnext[((long)(b * PQ + p)) * 2 + co] = v;
}

__global__ void out_k(const float* __restrict__ CENT, const float* __restrict__ HMP,
                      void* __restrict__ out, const unsigned* __restrict__ FLAGS)
{
  int t = blockIdx.x * 256 + threadIdx.x;
  if (t >= 2 * 12 * PQ) return;
  int p = t % PQ; int r = t / PQ; int ch = r % 12; int b = r / 12;
  float v = (ch < 2) ? CENT[((long)(b * 2 + ch)) * PQ + p]
                     : HMP[((long)(b * 10 + ch - 2)) * PQ + p];
  if (FLAGS[0]) ((bf16*)out)[t] = __float2bfloat16(v);
  else          ((float*)out)[t] = v;
}

// ---------------------------------------------------------------------------
extern "C" void kernel_launch(void* const* d_in, const int* in_sizes, int n_in,
                              void* d_out, int out_size, void* d_ws, size_t ws_size,
                              hipStream_t stream)
{
  (void)n_in; (void)out_size;

  // ---- workspace layout (~80 MB base; HBUF2 added past it if ws allows) ---
  float* F = (float*)d_ws;
  size_t off = 0;
  int aoff[42];
  {
    size_t acc = 0;
    for (int i = 2; i < 42; i++) { aoff[i] = (int)acc; acc += (size_t)in_sizes[i]; }
    off = acc;
  }
  float* ARENA = F;
  float* LIDF = F + off;                        // [2][128][HW] fp32 (dead after gather)
  bf16*  KVT16 = (bf16*)(F + off);              // alias: [2][256][HW] bf16 (decoder)
  off += 8294400;
  float* HBUF = F + off;                        // [1][128][HW] fp32 (per-batch fallback)
  bf16*  KPET16 = (bf16*)(F + off);             // alias: [128][HW] bf16 (decoder)
  float* PART  = F + off;                       // alias: [2][8][NSPLIT][200][18]
  off += 4147200;
  bf16*  CAMF16 = (bf16*)(F + off);             // [2][128][HW] bf16 (live all run)
  off += 4147200;
  float* HEAT  = F + off;                       // [2][10][HW] (dead after nms)
  float* SCORE = F + off + 648000;              // (dead after collect)
  off += 1296000;
  float* X   = F + off; off += 51200;           // decoder smalls — all dead during
  float* XQ  = F + off; off += 51200;           // convs; WB_* aliases this region
  float* QPE = F + off; off += 51200;
  float* T1Q = F + off; off += 51200;
  float* SQKV = F + off; off += 153600;
  float* SAO = F + off; off += 51200;
  float* PRE = F + off; off += 51200;
  float* QH2 = F + off; off += 51200;
  float* CAO = F + off; off += 51200;
  float* FF1 = F + off; off += 102400;
  float* YC  = F + off; off += 51200;           // X..YC span = 716800 floats
  float* CENT = F + off; off += 800;
  float* HMP = F + off; off += 4000;
  float* QPA = F + off; off += 800;
  float* QPB = F + off; off += 800;
  unsigned* U = (unsigned*)(F + off);
  unsigned* HIST  = U;                          // [0, 8192)
  unsigned* ACNT  = U + 8192;                   // 2
  unsigned* THR   = U + 8194;                   // 2
  unsigned* FLAGS = U + 8196;                   // 2 (NOT zeroed by zero_u32)
  unsigned* TOPC  = U + 8198;                   // 400
  unsigned* TOPI  = U + 8598;                   // 400
  unsigned long long* CAND = (unsigned long long*)(U + 9000); // 2*CAP u64
  size_t end_floats = off + 9000 + 2 * CAP * 2; // U scalars + CAND (u64=2 floats)
  // 2-batch HBUF for merged hm1/hm2 (z=2) if the workspace allows.
  float* HBUF2 = nullptr;
  if (ws_size >= (end_floats + 8294400) * sizeof(float))
    HBUF2 = F + end_floats;
  // 16-bit MFMA weight planes: alias the decoder-smalls region (dead during
  // wprep + convs). 1,327,104 shorts = 663,552 floats fits 716,800-float span.
  short* WB_LID = (short*)((((uintptr_t)X) + 15) & ~(uintptr_t)15);
  short* WB_CAM = WB_LID + 884736;              // 2*9*12*8*512 = 884736
  short* WB_HM1 = WB_CAM + 110592;              // 1*9*3*8*512  = 110592
  short* WB_HM2 = WB_HM1 + 294912;              // 2*9*4*8*512  = 294912 (+36864)

  auto W = [&](int i) -> const float* { return ARENA + aoff[i]; };

  // ---- dtype detect + weight conversion -----------------------------------
  detect_k<<<1, 256, 0, stream>>>((const unsigned*)d_in[0], FLAGS);
  {
    CvtArgs a;
    for (int i = 2; i < 42; i++) { a.src[i - 2] = d_in[i]; a.n[i - 2] = in_sizes[i]; a.off[i - 2] = aoff[i]; }
    cvt_k<<<dim3(432, 40), 256, 0, stream>>>(a, ARENA, FLAGS);
  }
  // input convs: dynamic planes (bf16 bits when FLAGS=1, fp16 split else)
  wprep_k<<<3456, 256, 0, stream>>>(W(2), WB_LID, 128, 384, 12, 8, 1, FLAGS, 1);
  wprep_k<<<432, 256, 0, stream>>>(W(4), WB_CAM, 128, 80, 3, 8, 0, FLAGS, 1);
  // hm convs consume computed fp32 features: always fp16 split
  wprep_k<<<1152, 256, 0, stream>>>(W(6), WB_HM1, 128, 128, 4, 8, 1, FLAGS, 0);
  wprep_k<<<144, 256, 0, stream>>>(W(10), WB_HM2, 10, 128, 4, 1, 1, FLAGS, 0);

  auto gemm = [&](const float* A, const float* A2, int lda, const float* Wp,
                  const float* bias, int act, const float* res, float* C, int ldc,
                  int M, int N, int K) {
    dim3 grid((M + 63) / 64, (N + 63) / 64, 1);
    gemm_k<float, float><<<grid, 256, 0, stream>>>(
        A, A2, lda, 0, 0L, Wp, bias, act, res,
        nullptr, nullptr, nullptr, nullptr, C, ldc, 0, 0L, M, N, K);
  };

  // ---- backbone convs (R2 geometry + R15 batched staging) -----------------
  conv_mfma<1, 1, 4, 4, 2, 60, float><<<dim3(544, 1, 2), 256, 0, stream>>>(
      d_in[0], FLAGS, 1, 1, (long)384 * HW, WB_LID, W(3), nullptr, nullptr, 0,
      LIDF, (long)128 * HW, 128, 384, 12, 8);
  conv_mfma<3, 1, 4, 4, 2, 60, float><<<dim3(544, 1, 2), 256, 0, stream>>>(
      d_in[0], FLAGS, 1, 0, (long)384 * HW, WB_LID, W(3), nullptr, nullptr, 0,
      LIDF, (long)128 * HW, 128, 384, 12, 8);
  conv_mfma<1, 1, 4, 4, 2, 60, bf16><<<dim3(544, 1, 2), 256, 0, stream>>>(
      d_in[1], FLAGS, 1, 1, (long)80 * HW, WB_CAM, W(5), nullptr, nullptr, 0,
      CAMF16, (long)128 * HW, 128, 80, 3, 8);
  conv_mfma<0, 1, 4, 4, 2, 60, bf16><<<dim3(544, 1, 2), 256, 0, stream>>>(
      d_in[1], FLAGS, 1, 0, (long)80 * HW, WB_CAM, W(5), nullptr, nullptr, 0,
      CAMF16, (long)128 * HW, 128, 80, 3, 8);
  if (HBUF2) {
    conv_mfma<3, 1, 4, 4, 2, 60, float><<<dim3(544, 1, 2), 256, 0, stream>>>(
        LIDF, FLAGS, 0, -1, (long)128 * HW, WB_HM1, W(7), W(8), W(9), 1,
        HBUF2, (long)128 * HW, 128, 128, 4, 8);
    conv_mfma<3, 4, 1, 1, 1, 60, float><<<dim3(544, 1, 2), 256, 0, stream>>>(
        HBUF2, FLAGS, 0, -1, (long)128 * HW, WB_HM2, W(11), nullptr, nullptr, 2,
        HEAT, (long)NCLS * HW, 10, 128, 4, 1);
  } else {
    for (int b = 0; b < 2; b++) {
      conv_mfma<3, 1, 4, 4, 2, 60, float><<<dim3(544, 1, 1), 256, 0, stream>>>(
          LIDF + (long)b * 128 * HW, FLAGS, 0, -1, 0L, WB_HM1, W(7), W(8), W(9), 1,
          HBUF, 0L, 128, 128, 4, 8);
      conv_mfma<3, 4, 1, 1, 1, 60, float><<<dim3(544, 1, 1), 256, 0, stream>>>(
          HBUF, FLAGS, 0, -1, 0L, WB_HM2, W(11), nullptr, nullptr, 2,
          HEAT + (long)b * NCLS * HW, 0L, 10, 128, 4, 1);
    }
  }

  // ---- NMS + exact top-200 ------------------------------------------------
  nms_k<<<(2 * NCLS * HW + 255) / 256, 256, 0, stream>>>(HEAT, SCORE);
  zero_u32<<<(8196 + 255) / 256, 256, 0, stream>>>(U, 8196);
  hist_k<<<dim3(240, 2), 256, 0, stream>>>(SCORE, HIST);
  thresh_k<<<2, 256, 0, stream>>>(HIST, THR);
  collect_k<<<(2 * NCLS * HW + 255) / 256, 256, 0, stream>>>(SCORE, THR, ACNT, CAND);
  select_k<<<2, 64, 0, stream>>>(CAND, ACNT, TOPC, TOPI, QPA);
  gather_k<<<200, 256, 0, stream>>>(LIDF, TOPC, TOPI, W(12), W(13), X);

  // ---- decoder layers -----------------------------------------------------
  for (int i = 0; i < 2; i++) {
    const float* qcur = (i == 0) ? QPA : QPB;
    float* qnext = (i == 0) ? QPB : QPA;
    // query pos-embed fused into GEMM staging (amode 3, A = qpos)
    gemm_k<float, float><<<dim3(7, 2, 1), 256, 0, stream>>>(
        qcur, (const float*)nullptr, 0, 3, 0L,
        W(18) + (size_t)(i * 2 + 0) * 16384, W(19) + (i * 2 + 0) * 128, 0, nullptr,
        W(14) + (i * 2 + 0) * 256, W(15) + (i * 2 + 0) * 128,
        W(16) + (i * 2 + 0) * 128, W(17) + (i * 2 + 0) * 128,
        QPE, 128, 0, 0L, 400, 128, 128);
    // key pos-embed (BEV grid fused), bf16 MFMA, stored transposed [128][HW]
    kpe_mfma_k<<<dim3(507, 2), 256, 0, stream>>>(
        W(14) + (i * 2 + 1) * 256, W(15) + (i * 2 + 1) * 128,
        W(16) + (i * 2 + 1) * 128, W(17) + (i * 2 + 1) * 128,
        W(18) + (size_t)(i * 2 + 1) * 16384, W(19) + (i * 2 + 1) * 128,
        KPET16);
    // self-attention (X+QPE fused via A2)
    gemm(X, QPE, 128, W(20) + (size_t)(i * 2 + 0) * 49152, W(21) + (i * 2 + 0) * 384,
         0, nullptr, SQKV, 384, 400, 384, 128);
    self_attn_k<<<dim3(200, 8, 2), 64, 0, stream>>>(SQKV, SAO);
    gemm(SAO, nullptr, 128, W(22) + (size_t)(i * 2 + 0) * 16384, W(23) + (i * 2 + 0) * 128,
         0, X, PRE, 128, 400, 128, 128);
    ln_k<<<100, 256, 0, stream>>>(PRE, W(24) + (i * 3 + 0) * 128, W(25) + (i * 3 + 0) * 128, X);
    // cross-attention Q projection (X+QPE fused via A2) — N=128 (Q rows only)
    gemm(X, QPE, 128, W(20) + (size_t)(i * 2 + 1) * 49152, W(21) + (i * 2 + 1) * 384,
         0, nullptr, QH2, 128, 400, 128, 128);
    kvproj_k<<<dim3(507, 2, 2), 256, 0, stream>>>(
        CAMF16, KPET16,
        W(20) + (size_t)(i * 2 + 1) * 49152 + 16384,
        W(21) + (i * 2 + 1) * 384 + 128, KVT16);
    flash_mfma_k<<<dim3(NSPLIT, 8, 8), 256, 0, stream>>>(QH2, KVT16, PART);
    combine_k<<<200, 256, 0, stream>>>(PART, CAO);
    gemm(CAO, nullptr, 128, W(22) + (size_t)(i * 2 + 1) * 16384, W(23) + (i * 2 + 1) * 128,
         0, X, PRE, 128, 400, 128, 128);
    ln_k<<<100, 256, 0, stream>>>(PRE, W(24) + (i * 3 + 1) * 128, W(25) + (i * 3 + 1) * 128, X);
    // FFN
    gemm(X, nullptr, 128, W(26) + (size_t)i * 32768, W(27) + i * 256,
         1, nullptr, FF1, 256, 400, 256, 128);
    gemm(FF1, nullptr, 256, W(28) + (size_t)i * 32768, W(29) + i * 128,
         0, X, PRE, 128, 400, 128, 256);
    ln_k<<<100, 256, 0, stream>>>(PRE, W(24) + (i * 3 + 2) * 128, W(25) + (i * 3 + 2) * 128, X);
    // prediction heads
    conv1d_k<<<dim3(200, 2), 128, 0, stream>>>(X, W(30) + (size_t)i * 49152,
        W(31) + i * 128, W(32) + i * 128, W(33) + i * 128, YC);
    head2_k<<<4, 256, 0, stream>>>(YC, W(34) + (size_t)i * 768, W(35) + i * 2,
        qcur, CENT, 2, qnext);
    conv1d_k<<<dim3(200, 2), 128, 0, stream>>>(X, W(36) + (size_t)i * 49152,
        W(37) + i * 128, W(38) + i * 128, W(39) + i * 128, YC);
    head2_k<<<16, 256, 0, stream>>>(YC, W(40) + (size_t)i * 3840, W(41) + i * 10,
        nullptr, HMP, 10, nullptr);
  }
  out_k<<<19, 256, 0, stream>>>(CENT, HMP, d_out, FLAGS);
}

// Round 7
// 1914.629 us; speedup vs baseline: 1.1939x; 1.1939x over previous
//
#include <hip/hip_runtime.h>
#include <hip/hip_bf16.h>

typedef __hip_bfloat16 bf16;
typedef _Float16 f16;

#define HW 32400
#define NCLS 10
#define PQ 200
#define HIDDEN 128
#define NSPLIT 45
#define SPLITLEN 720    // 45*720 = 32400 exactly
#define CHK 32
#define CAP 6144
#define NBIN 4096
#define L2E 1.44269504f

typedef __attribute__((ext_vector_type(8))) _Float16 half8;
typedef __attribute__((ext_vector_type(8))) short short8;
typedef __attribute__((ext_vector_type(4))) short short4v;
typedef __attribute__((ext_vector_type(4))) float f32x4;

__device__ __forceinline__ float b2f(bf16 v) { return __bfloat162float(v); }
__device__ __forceinline__ void stf(float* p, float v) { *p = v; }
__device__ __forceinline__ void stf(bf16* p, float v) { *p = __float2bfloat16(v); }
// runtime-dtype load: isbf!=0 -> bf16 array, else fp32 array
__device__ __forceinline__ float ldsel(const void* p, long i, unsigned isbf) {
  return isbf ? __bfloat162float(((const bf16*)p)[i]) : ((const float*)p)[i];
}
__device__ __forceinline__ float ldf(const float* p, long i) { return p[i]; }
__device__ __forceinline__ float ldf(const bf16* p, long i) { return __bfloat162float(p[i]); }
__device__ __forceinline__ short f2bf_bits(float v) {
  union { bf16 h; short s; } u; u.h = __float2bfloat16(v); return u.s;
}
__device__ __forceinline__ short f2h_bits(float v) {
  union { f16 h; short s; } u; u.h = (f16)v; return u.s;
}

// ---------------------------------------------------------------------------
// dtype detection (bf16 vs fp32 inputs) -> FLAGS[0]
// ---------------------------------------------------------------------------
__global__ void detect_k(const unsigned* __restrict__ L, unsigned* __restrict__ FLAGS)
{
  __shared__ unsigned cnt[2];
  int tid = threadIdx.x;
  if (tid < 2) cnt[tid] = 0;
  __syncthreads();
  unsigned nz = 0, pl = 0;
  for (int w = tid; w < 4096; w += 256) {
    unsigned u = L[w];
    if (u) {
      nz++;
      unsigned e = (u >> 7) & 0xFF;
      if (e >= 110 && e <= 140) pl++;
    }
  }
  atomicAdd(&cnt[0], nz);
  atomicAdd(&cnt[1], pl);
  __syncthreads();
  if (tid == 0) {
    FLAGS[0] = (2u * cnt[1] > cnt[0]) ? 1u : 0u;
    FLAGS[1] = 0u;
  }
}

// batched weight conversion into fp32 arena (exact in both modes)
struct CvtArgs { const void* src[40]; int n[40]; int off[40]; };
__global__ __launch_bounds__(256) void cvt_k(CvtArgs a, float* __restrict__ dst,
                                             const unsigned* __restrict__ FLAGS)
{
  int j = blockIdx.y;
  unsigned isbf = FLAGS[0];
  int n = a.n[j];
  const void* s = a.src[j];
  float* d = dst + a.off[j];
  for (int t = blockIdx.x * 256 + threadIdx.x; t < n; t += gridDim.x * 256)
    d[t] = ldsel(s, t, isbf);
}

// ---------------------------------------------------------------------------
// Conv weight pre-swizzle into MFMA fragment order (16-bit planes).
// WB[plane][tap][kb][nt][n16][k32] ; value = W[nt*16+n16][kb*32+k][ty][tx]
// dynmode=1 and FLAGS[0]=1 (bf16 weights): plane0 = bf16 bits (exact), p1=0.
// else: plane0 = fp16 hi, plane1 = fp16((v - hi) * 4096)  (fp32-split).
// ---------------------------------------------------------------------------
__global__ __launch_bounds__(256) void wprep_k(const float* __restrict__ Wsrc,
    short* __restrict__ WB, int N, int K, int KB, int NTG, int split,
    const unsigned* __restrict__ FLAGS, int dynmode)
{
  unsigned isbf = dynmode ? FLAGS[0] : 0u;
  long total = (long)(split ? 2 : 1) * 9 * KB * NTG * 512;
  for (long t = (long)blockIdx.x * 256 + threadIdx.x; t < total;
       t += (long)gridDim.x * 256) {
    long r = t;
    int k = (int)(r & 31); r >>= 5;
    int n16 = (int)(r & 15); r >>= 4;
    int nt = (int)(r % NTG); r /= NTG;
    int kb = (int)(r % KB); r /= KB;
    int tap = (int)(r % 9); r /= 9;
    int plane = (int)r;
    int n = nt * 16 + n16, kk = kb * 32 + k;
    float v = 0.f;
    if (n < N && kk < K) v = Wsrc[((long)n * K + kk) * 9 + tap];
    short outv;
    if (isbf) {
      outv = (plane == 0) ? f2bf_bits(v) : (short)0;
    } else {
      f16 h = (f16)v;
      if (plane == 0) outv = f2h_bits((float)h);
      else outv = f2h_bits((v - (float)h) * 4096.0f);
    }
    WB[t] = outv;
  }
}

// ---------------------------------------------------------------------------
// MFMA conv2d 3x3 SAME as 9 shifted GEMMs over CW-pixel row chunks.
// MODE 3: fp32-accurate fp16 split (3 MFMAs).  MODE 0: plain fp16.
// MODE 1: exact bf16 (input already bf16: raw-bit staging, 1 bf16 MFMA).
// MODE 2: fp32 input rounded to bf16 (1 bf16 MFMA) — used for hm convs in
//   bf16 mode, where the JAX reference itself consumes a bf16 tensor; our
//   round(LIDF fp32 -> bf16) equals the reference's lidar_feat bits exactly.
// gate: -1 always run; 0/1 run only when FLAGS[0] matches (dual-launch).
// STAGING = R2/R14 inline loop, VGPR ~76. LEDGER (do not retry): R12 CW=30
// (more phases, slower); R13 reg-prefetch & R15 batched staging (both +80
// VGPR -> occupancy 10%, ~2.2x slower). Any scheme holding a kb-tile in
// registers pays the VGPR peak; the inline loop is the local optimum.
// ---------------------------------------------------------------------------
template <int MODE, int WM, int WN, int MT, int NT, int CW, typename CT>
__global__ __launch_bounds__(256) void conv_mfma(
    const void* __restrict__ A, const unsigned* __restrict__ FLAGS, int dyn,
    int gate, long abatch,
    const short* __restrict__ WB, const float* __restrict__ bias,
    const float* __restrict__ g, const float* __restrict__ beta, int act,
    CT* __restrict__ C, long cbatch, int N, int K, int KB, int NTG)
{
  constexpr bool BF = (MODE == 1 || MODE == 2);
  constexpr int CPR = 180 / CW;              // chunks per row
  constexpr int TOT = 180 * CPR;             // total chunks
  constexpr int BAND = (TOT + 7) / 8;        // chunks per XCD band
  constexpr int PXS = WM * MT * 16 + 2;      // staged px per row (+2 halo)
  constexpr int AW = 3 * PXS * 40;           // [ty][px][k] k-stride 40 (shorts)
  __shared__ __align__(16) short Ah[AW];
  __shared__ __align__(16) short Al[MODE == 3 ? AW : 8];
  if (gate >= 0 && FLAGS[0] != (unsigned)gate) return;
  // XCD band swizzle: idx = (g&7)*BAND + (g>>3)
  int gsw = blockIdx.x;
  int idx = (gsw & 7) * BAND + (gsw >> 3);
  if (idx >= TOT) return;
  unsigned isbf = dyn ? FLAGS[0] : 0u;
  int bz = blockIdx.z;
  int y = idx / CPR;
  int x0 = (idx % CPR) * CW;
  int tid = threadIdx.x;
  int w = tid >> 6, lane = tid & 63;
  int lane15 = lane & 15, lgrp = lane >> 4;
  int wm = w % WM, wn = w / WM;
  int mbase = wm * MT * 16;
  int nbase = wn * NT * 16;
  f32x4 accM[MT][NT] = {};
  f32x4 accC[MODE == 3 ? MT : 1][MODE == 3 ? NT : 1] = {};
  long planeStride = (long)9 * KB * NTG * 512;

  for (int kb = 0; kb < KB; kb++) {
    __syncthreads();
    // inline staging: 3 rows x PXS px x 4 k-groups of 8 (one short8 each)
    for (int u = tid; u < 3 * PXS * 4; u += 256) {
      int px = u % PXS;
      int t2 = u / PXS;
      int kg = t2 & 3, row = t2 >> 2;
      int gx = x0 + px - 1, gy = y + row - 1;
      bool in = (gx >= 0 && gx < 180 && gy >= 0 && gy < 180);
      long gbase = (long)bz * abatch + (long)(kb * 32 + kg * 8) * HW +
                   (long)gy * 180 + gx;
      short8 hv, lv;
#pragma unroll
      for (int j = 0; j < 8; j++) {
        int kk = kb * 32 + kg * 8 + j;
        if constexpr (MODE == 1) {
          // input already bf16: copy bits directly (exact)
          hv[j] = (in && kk < K) ? ((const short*)A)[gbase + (long)j * HW]
                                 : (short)0;
        } else if constexpr (MODE == 2) {
          // fp32 input rounded to bf16 (matches reference's bf16 tensor)
          float v = (in && kk < K) ? ((const float*)A)[gbase + (long)j * HW]
                                   : 0.f;
          hv[j] = f2bf_bits(v);
        } else {
          float v = (in && kk < K) ? ldsel(A, gbase + (long)j * HW, isbf) : 0.f;
          f16 h = (f16)v;
          hv[j] = f2h_bits((float)h);
          if constexpr (MODE == 3) lv[j] = f2h_bits((v - (float)h) * 4096.0f);
        }
      }
      int o = (row * PXS + px) * 40 + kg * 8;  // *2B: px-stride 80, 16B aligned
      *(short8*)&Ah[o] = hv;
      if constexpr (MODE == 3) *(short8*)&Al[o] = lv;
    }
    __syncthreads();
#pragma unroll
    for (int tap = 0; tap < 9; tap++) {
      int ty = tap / 3, tx = tap % 3;
      const short* wb = WB + (((long)tap * KB + kb) * NTG) * 512;
      if constexpr (BF) {
        short8 bh[NT];
#pragma unroll
        for (int nt = 0; nt < NT; nt++) {
          long o = (long)(wn * NT + nt) * 512 + lane15 * 32 + lgrp * 8;
          bh[nt] = *(const short8*)(wb + o);
        }
        short8 ah[MT];
#pragma unroll
        for (int mt = 0; mt < MT; mt++) {
          int px = mbase + mt * 16 + lane15 + tx;
          ah[mt] = *(const short8*)&Ah[(ty * PXS + px) * 40 + lgrp * 8];
        }
#pragma unroll
        for (int mt = 0; mt < MT; mt++)
#pragma unroll
          for (int nt = 0; nt < NT; nt++)
            accM[mt][nt] = __builtin_amdgcn_mfma_f32_16x16x32_bf16(
                ah[mt], bh[nt], accM[mt][nt], 0, 0, 0);
      } else {
        half8 bh[NT], bl[MODE == 3 ? NT : 1];
#pragma unroll
        for (int nt = 0; nt < NT; nt++) {
          long o = (long)(wn * NT + nt) * 512 + lane15 * 32 + lgrp * 8;
          bh[nt] = *(const half8*)(wb + o);
          if constexpr (MODE == 3) bl[nt] = *(const half8*)(wb + planeStride + o);
        }
        half8 ah[MT], al[MODE == 3 ? MT : 1];
#pragma unroll
        for (int mt = 0; mt < MT; mt++) {
          int px = mbase + mt * 16 + lane15 + tx;
          int o = (ty * PXS + px) * 40 + lgrp * 8;
          ah[mt] = *(const half8*)&Ah[o];
          if constexpr (MODE == 3) al[mt] = *(const half8*)&Al[o];
        }
#pragma unroll
        for (int mt = 0; mt < MT; mt++)
#pragma unroll
          for (int nt = 0; nt < NT; nt++) {
            accM[mt][nt] = __builtin_amdgcn_mfma_f32_16x16x32_f16(
                ah[mt], bh[nt], accM[mt][nt], 0, 0, 0);
            if constexpr (MODE == 3) {
              accC[mt][nt] = __builtin_amdgcn_mfma_f32_16x16x32_f16(
                  al[mt], bh[nt], accC[mt][nt], 0, 0, 0);
              accC[mt][nt] = __builtin_amdgcn_mfma_f32_16x16x32_f16(
                  ah[mt], bl[nt], accC[mt][nt], 0, 0, 0);
            }
          }
      }
    }
  }
  int pixbase = y * 180 + x0;
#pragma unroll
  for (int mt = 0; mt < MT; mt++) {
    int m = mbase + mt * 16 + lgrp * 4;
    if (m >= CW) continue;
#pragma unroll
    for (int nt = 0; nt < NT; nt++) {
      int n = nbase + nt * 16 + lane15;
      if (n >= N) continue;
      float bi = bias[n];
      float gg = g ? g[n] : 1.f;
      float bb = g ? beta[n] : 0.f;
      long base = (long)bz * cbatch + (long)n * HW + pixbase + m;
      float vv[4];
#pragma unroll
      for (int r = 0; r < 4; r++) {
        float v = accM[mt][nt][r];
        if constexpr (MODE == 3) v += accC[mt][nt][r] * (1.f / 4096.f);
        v += bi;
        if (g) v = v * gg + bb;
        if (act == 1) v = fmaxf(v, 0.f);
        else if (act == 2) v = 1.f / (1.f + expf(-v));
        vv[r] = v;
      }
      if constexpr (sizeof(CT) == 4) {
        if (m + 3 < CW) {
          f32x4 ov; ov[0] = vv[0]; ov[1] = vv[1]; ov[2] = vv[2]; ov[3] = vv[3];
          *(f32x4*)&C[base] = ov;
        } else {
#pragma unroll
          for (int r = 0; r < 4; r++) if (m + r < CW) C[base + r] = vv[r];
        }
      } else {
        if (m + 3 < CW) {
          short4v ov;
#pragma unroll
          for (int r = 0; r < 4; r++) ov[r] = f2bf_bits(vv[r]);
          *(short4v*)&C[base] = ov;
        } else {
#pragma unroll
          for (int r = 0; r < 4; r++)
            if (m + r < CW) *((short*)&C[base + r]) = f2bf_bits(vv[r]);
        }
      }
    }
  }
}

// ---------------------------------------------------------------------------
// bf16 MFMA KV projection: C = (A1+A2) @ W^T + bias.
// y-merged (R15): each block covers 128 of 256 output rows (NT=4, grid y=2).
// ---------------------------------------------------------------------------
__global__ __launch_bounds__(256) void kvproj_k(
    const bf16* __restrict__ A1, const bf16* __restrict__ A2,
    const float* __restrict__ Wf, const float* __restrict__ bias,
    bf16* __restrict__ C)
{
  __shared__ __align__(16) short As[64 * 40];
  int m0 = blockIdx.x * 64;
  int n0 = blockIdx.y * 128;
  int b = blockIdx.z;
  int tid = threadIdx.x;
  int w = tid >> 6, lane = tid & 63;
  int lane15 = lane & 15, lgrp = lane >> 4;
  int wm = w & 1, wn = w >> 1;
  const bf16* A1b = A1 + (long)b * 128 * HW;
  f32x4 acc[2][4] = {};
  for (int kb = 0; kb < 4; kb++) {
    __syncthreads();
    for (int e = tid; e < 2048; e += 256) {
      int k = e >> 6, m = e & 63;
      int gm = m0 + m;
      float v = 0.f;
      if (gm < HW) {
        long idx = (long)(kb * 32 + k) * HW + gm;
        v = b2f(A1b[idx]) + b2f(A2[idx]);
      }
      As[m * 40 + k] = f2bf_bits(v);
    }
    __syncthreads();
    short8 bh[4];
#pragma unroll
    for (int nt = 0; nt < 4; nt++) {
      int n = n0 + wn * 64 + nt * 16 + lane15;
      const float* wr = Wf + (long)n * 128 + kb * 32 + lgrp * 8;
      float4 w0 = *(const float4*)wr;
      float4 w1 = *(const float4*)(wr + 4);
      short8 t;
      t[0] = f2bf_bits(w0.x); t[1] = f2bf_bits(w0.y);
      t[2] = f2bf_bits(w0.z); t[3] = f2bf_bits(w0.w);
      t[4] = f2bf_bits(w1.x); t[5] = f2bf_bits(w1.y);
      t[6] = f2bf_bits(w1.z); t[7] = f2bf_bits(w1.w);
      bh[nt] = t;
    }
    short8 ah[2];
#pragma unroll
    for (int mt = 0; mt < 2; mt++) {
      int m = wm * 32 + mt * 16 + lane15;
      ah[mt] = *(const short8*)&As[m * 40 + lgrp * 8];
    }
#pragma unroll
    for (int mt = 0; mt < 2; mt++)
#pragma unroll
      for (int nt = 0; nt < 4; nt++)
        acc[mt][nt] = __builtin_amdgcn_mfma_f32_16x16x32_bf16(
            ah[mt], bh[nt], acc[mt][nt], 0, 0, 0);
  }
#pragma unroll
  for (int mt = 0; mt < 2; mt++) {
    int mq = m0 + wm * 32 + mt * 16 + lgrp * 4;
    if (mq >= HW) continue;
#pragma unroll
    for (int nt = 0; nt < 4; nt++) {
      int n = n0 + wn * 64 + nt * 16 + lane15;
      float bi = bias[n];
      short4v ov;
#pragma unroll
      for (int r = 0; r < 4; r++) ov[r] = f2bf_bits(acc[mt][nt][r] + bi);
      *(short4v*)&C[(long)b * 256 * HW + (long)n * HW + mq] = ov;
    }
  }
}

// ---------------------------------------------------------------------------
// bf16 MFMA KPE projection: KPET[n][m] = posembed_relu(m) @ W2^T + b2.
// ---------------------------------------------------------------------------
__global__ __launch_bounds__(256) void kpe_mfma_k(
    const float* __restrict__ pe1w, const float* __restrict__ pe1b,
    const float* __restrict__ pe1g, const float* __restrict__ pe1bt,
    const float* __restrict__ W2, const float* __restrict__ b2,
    bf16* __restrict__ C)
{
  __shared__ __align__(16) short As[64 * 40];
  int m0 = blockIdx.x * 64;
  int n0 = blockIdx.y * 64;
  int tid = threadIdx.x;
  int w = tid >> 6, lane = tid & 63;
  int lane15 = lane & 15, lgrp = lane >> 4;
  int wm = w & 1, wn = w >> 1;
  f32x4 acc[2][2] = {};
  for (int kb = 0; kb < 4; kb++) {
    __syncthreads();
    for (int e = tid; e < 2048; e += 256) {
      int k = e >> 6, m = e & 63;
      int gm = m0 + m;
      int kk = kb * 32 + k;
      float v = 0.f;
      if (gm < HW) {
        float p0 = (float)(gm / 180) + 0.5f;
        float p1 = (float)(gm % 180) + 0.5f;
        float t = p0 * pe1w[kk * 2] + p1 * pe1w[kk * 2 + 1] + pe1b[kk];
        t = t * pe1g[kk] + pe1bt[kk];
        v = fmaxf(t, 0.f);
      }
      As[m * 40 + k] = f2bf_bits(v);
    }
    __syncthreads();
    short8 bh[2];
#pragma unroll
    for (int nt = 0; nt < 2; nt++) {
      int n = n0 + wn * 32 + nt * 16 + lane15;
      const float* wr = W2 + (long)n * 128 + kb * 32 + lgrp * 8;
      float4 w0 = *(const float4*)wr;
      float4 w1 = *(const float4*)(wr + 4);
      short8 t;
      t[0] = f2bf_bits(w0.x); t[1] = f2bf_bits(w0.y);
      t[2] = f2bf_bits(w0.z); t[3] = f2bf_bits(w0.w);
      t[4] = f2bf_bits(w1.x); t[5] = f2bf_bits(w1.y);
      t[6] = f2bf_bits(w1.z); t[7] = f2bf_bits(w1.w);
      bh[nt] = t;
    }
    short8 ah[2];
#pragma unroll
    for (int mt = 0; mt < 2; mt++) {
      int m = wm * 32 + mt * 16 + lane15;
      ah[mt] = *(const short8*)&As[m * 40 + lgrp * 8];
    }
#pragma unroll
    for (int mt = 0; mt < 2; mt++)
#pragma unroll
      for (int nt = 0; nt < 2; nt++)
        acc[mt][nt] = __builtin_amdgcn_mfma_f32_16x16x32_bf16(
            ah[mt], bh[nt], acc[mt][nt], 0, 0, 0);
  }
#pragma unroll
  for (int mt = 0; mt < 2; mt++) {
    int mq = m0 + wm * 32 + mt * 16 + lgrp * 4;
    if (mq >= HW) continue;   // mq 4-aligned, HW%4==0 -> vector store safe
#pragma unroll
    for (int nt = 0; nt < 2; nt++) {
      int n = n0 + wn * 32 + nt * 16 + lane15;
      float bi = b2[n];
      short4v ov;
#pragma unroll
      for (int r = 0; r < 4; r++) ov[r] = f2bf_bits(acc[mt][nt][r] + bi);
      *(short4v*)&C[(long)n * HW + mq] = ov;
    }
  }
}

// ---------------------------------------------------------------------------
// Generic tiled GEMM: C = act((A [+A2]) @ W^T + bias) (+ res)
// amode 0: A[m*lda+k] (+A2 same layout).  amode 3: fused QUERY pos-embed.
// cmode 0: C[m*ldc+n] ; cmode 1: C[n*ldc+m].  K multiple of 16.
// ---------------------------------------------------------------------------
template <typename AT, typename CT>
__global__ __launch_bounds__(256) void gemm_k(
    const AT* __restrict__ A, const AT* __restrict__ A2, int lda, int amode,
    long abatch,
    const float* __restrict__ W, const float* __restrict__ bias, int act,
    const float* __restrict__ res,
    const float* __restrict__ pe1w, const float* __restrict__ pe1b,
    const float* __restrict__ pe1g, const float* __restrict__ pe1bt,
    CT* __restrict__ C, int ldc, int cmode, long cbatch,
    int M, int N, int K)
{
  __shared__ __align__(16) float As[16][68];
  __shared__ __align__(16) float Ws[16][68];
  int b = blockIdx.z;
  int m0 = blockIdx.x * 64, n0 = blockIdx.y * 64;
  int tid = threadIdx.x;
  int nt = tid & 15, mt = tid >> 4;
  float acc[4][4] = {};
  const AT* Ab = A + (long)b * abatch;
  for (int k0 = 0; k0 < K; k0 += 16) {
    if (amode == 0) {
      for (int e = tid; e < 1024; e += 256) {
        int m = e >> 4, k = e & 15;
        float v = 0.f;
        if (m0 + m < M) {
          long idx = (long)(m0 + m) * lda + k0 + k;
          v = ldf(Ab, idx);
          if (A2) v += ldf(A2, idx);
        }
        As[k][m] = v;
      }
    } else { // amode 3: query pos-embed, A = qpos (fp32 [M][2])
      const float* qp = (const float*)A;
      for (int e = tid; e < 1024; e += 256) {
        int m = e & 63, k = e >> 6;
        float v = 0.f;
        int gm = m0 + m;
        if (gm < M) {
          float p0 = qp[gm * 2], p1 = qp[gm * 2 + 1];
          int kk = k0 + k;
          float t = p0 * pe1w[kk * 2] + p1 * pe1w[kk * 2 + 1] + pe1b[kk];
          t = t * pe1g[kk] + pe1bt[kk];
          v = fmaxf(t, 0.f);
        }
        As[k][m] = v;
      }
    }
    for (int e = tid; e < 1024; e += 256) {
      int n = e >> 4, k = e & 15;
      float v = 0.f;
      if (n0 + n < N) v = W[(long)(n0 + n) * K + k0 + k];
      Ws[k][n] = v;
    }
    __syncthreads();
#pragma unroll
    for (int kk = 0; kk < 16; kk++) {
      float4 av = *(const float4*)&As[kk][mt * 4];
      float4 wv = *(const float4*)&Ws[kk][nt * 4];
      float am[4] = {av.x, av.y, av.z, av.w};
      float wn[4] = {wv.x, wv.y, wv.z, wv.w};
#pragma unroll
      for (int mi = 0; mi < 4; mi++)
#pragma unroll
        for (int ni = 0; ni < 4; ni++)
          acc[mi][ni] = fmaf(am[mi], wn[ni], acc[mi][ni]);
    }
    __syncthreads();
  }
#pragma unroll
  for (int mi = 0; mi < 4; mi++) {
    int m = m0 + mt * 4 + mi;
    if (m >= M) continue;
#pragma unroll
    for (int ni = 0; ni < 4; ni++) {
      int n = n0 + nt * 4 + ni;
      if (n >= N) continue;
      float v = acc[mi][ni];
      if (bias) v += bias[n];
      if (act == 1) v = fmaxf(v, 0.f);
      if (res) v += res[(long)m * ldc + n];
      long ci = (cmode == 0) ? ((long)b * cbatch + (long)m * ldc + n)
                             : ((long)b * cbatch + (long)n * ldc + m);
      stf(&C[ci], v);
    }
  }
}

// ---------------------------------------------------------------------------
__global__ void nms_k(const float* __restrict__ HEAT, float* __restrict__ SCORE)
{
  int t = blockIdx.x * 256 + threadIdx.x;
  if (t >= 2 * NCLS * HW) return;
  int b = t / (NCLS * HW); int r = t % (NCLS * HW);
  int cls = r / HW; int n = r % HW;
  const float* hb = HEAT + ((long)(b * NCLS + cls)) * HW;
  float v = hb[n];
  bool keep = true;
  if (cls < 8) {
    int y = n / 180, x = n % 180;
    if (y == 0 || y == 179 || x == 0 || x == 179) keep = false;
    else {
      float mx = -1e30f;
#pragma unroll
      for (int dy = -1; dy <= 1; dy++)
#pragma unroll
        for (int dx = -1; dx <= 1; dx++)
          mx = fmaxf(mx, hb[(y + dy) * 180 + x + dx]);
      keep = (v == mx);
    }
  }
  SCORE[(long)b * (NCLS * HW) + r] = keep ? v : 0.f;
}

__global__ void zero_u32(unsigned* p, int n)
{
  int t = blockIdx.x * 256 + threadIdx.x;
  if (t < n) p[t] = 0;
}

__global__ __launch_bounds__(256) void hist_k(const float* __restrict__ SCORE,
                                              unsigned* __restrict__ HIST)
{
  __shared__ unsigned lh[NBIN];
  int b = blockIdx.y;
  for (int e = threadIdx.x; e < NBIN; e += 256) lh[e] = 0;
  __syncthreads();
  int start = blockIdx.x * 1350;
  const float* sb = SCORE + (long)b * (NCLS * HW);
  for (int e = start + threadIdx.x; e < start + 1350; e += 256) {
    unsigned bits = __float_as_uint(sb[e]);
    atomicAdd(&lh[bits >> 18], 1u);
  }
  __syncthreads();
  for (int e = threadIdx.x; e < NBIN; e += 256) {
    unsigned c = lh[e];
    if (c) atomicAdd(&HIST[b * NBIN + e], c);
  }
}

__global__ void thresh_k(const unsigned* __restrict__ HIST, unsigned* __restrict__ THR)
{
  __shared__ unsigned ps[256];
  int b = blockIdx.x;
  const unsigned* hb = HIST + b * NBIN;
  unsigned s = 0;
  for (int j = 0; j < 16; j++) s += hb[threadIdx.x * 16 + j];
  ps[threadIdx.x] = s;
  __syncthreads();
  if (threadIdx.x == 0) {
    unsigned cum = 0; int t = 255;
    for (; t > 0; t--) { if (cum + ps[t] >= PQ) break; cum += ps[t]; }
    int bin = t * 16 + 15;
    for (; bin > t * 16; bin--) { unsigned c = hb[bin]; if (cum + c >= PQ) break; cum += c; }
    if (bin < 1) bin = 1;
    THR[b] = (unsigned)bin;
  }
}

__global__ void collect_k(const float* __restrict__ SCORE, const unsigned* __restrict__ THR,
                          unsigned* __restrict__ ACNT, unsigned long long* __restrict__ CAND)
{
  int t = blockIdx.x * 256 + threadIdx.x;
  if (t >= 2 * NCLS * HW) return;
  int b = t / (NCLS * HW); int r = t % (NCLS * HW);
  float v = SCORE[(long)b * (NCLS * HW) + r];
  unsigned bits = __float_as_uint(v);
  if ((bits >> 18) >= THR[b]) {
    unsigned slot = atomicAdd(&ACNT[b], 1u);
    if (slot < CAP) CAND[(long)b * CAP + slot] =
        ((unsigned long long)bits << 32) | (unsigned)(~r);
  }
}

__global__ __launch_bounds__(64) void select_k(
    const unsigned long long* __restrict__ CAND, const unsigned* __restrict__ ACNT,
    unsigned* __restrict__ TOPC, unsigned* __restrict__ TOPI, float* __restrict__ QPA)
{
  __shared__ unsigned long long cnd[CAP];
  int b = blockIdx.x;
  int lane = threadIdx.x;
  unsigned cnt = ACNT[b]; if (cnt > CAP) cnt = CAP;
  for (int e = lane; e < (int)cnt; e += 64) cnd[e] = CAND[(long)b * CAP + e];
  __syncthreads();
  for (int p = 0; p < PQ; p++) {
    unsigned long long best = 0;
    for (int e = lane; e < (int)cnt; e += 64) { unsigned long long c = cnd[e]; if (c > best) best = c; }
#pragma unroll
    for (int o = 32; o; o >>= 1) {
      unsigned long long other = __shfl_xor(best, o, 64);
      if (other > best) best = other;
    }
    for (int e = lane; e < (int)cnt; e += 64) if (best != 0 && cnd[e] == best) cnd[e] = 0;
    if (lane == 0) {
      unsigned idx = (best == 0) ? 0u : ~(unsigned)(best & 0xFFFFFFFFull);
      if (idx >= NCLS * HW) idx = 0;
      unsigned cls = idx / HW, n = idx % HW;
      TOPC[b * PQ + p] = cls; TOPI[b * PQ + p] = n;
      QPA[((long)(b * PQ + p)) * 2 + 0] = (float)(n / 180) + 0.5f;
      QPA[((long)(b * PQ + p)) * 2 + 1] = (float)(n % 180) + 0.5f;
    }
    __syncthreads();
  }
}

__global__ void gather_k(const float* __restrict__ LIDF, const unsigned* __restrict__ TOPC,
                         const unsigned* __restrict__ TOPI, const float* __restrict__ cew,
                         const float* __restrict__ ceb, float* __restrict__ X)
{
  int t = blockIdx.x * 256 + threadIdx.x;
  if (t >= 2 * PQ * HIDDEN) return;
  int c = t & 127; int r = t >> 7; int p = r % PQ; int b = r / PQ;
  unsigned n = TOPI[b * PQ + p]; unsigned cls = TOPC[b * PQ + p];
  if (n >= HW) n = 0;
  if (cls >= NCLS) cls = 0;
  X[t] = LIDF[((long)(b * HIDDEN + c)) * HW + n] + cew[c * NCLS + cls] + ceb[c];
}

__global__ __launch_bounds__(64) void self_attn_k(const float* __restrict__ SQKV,
                                                  float* __restrict__ SAO)
{
  int q = blockIdx.x, h = blockIdx.y, b = blockIdx.z;
  int lane = threadIdx.x;
  const float* qp = SQKV + ((long)(b * PQ + q)) * 384 + h * 16;
  float qv[16];
#pragma unroll
  for (int d = 0; d < 16; d++) qv[d] = qp[d] * 0.25f;
  float sv[4]; int kks[4]; int nk = 0;
  float lmax = -1e30f;
  for (int kk = lane; kk < PQ; kk += 64) {
    const float* kp = SQKV + ((long)(b * PQ + kk)) * 384 + 128 + h * 16;
    float s = 0.f;
#pragma unroll
    for (int d = 0; d < 16; d++) s = fmaf(qv[d], kp[d], s);
    sv[nk] = s; kks[nk] = kk; nk++;
    lmax = fmaxf(lmax, s);
  }
#pragma unroll
  for (int o = 32; o; o >>= 1) lmax = fmaxf(lmax, __shfl_xor(lmax, o, 64));
  float lsum = 0.f; float acc[16] = {};
  for (int t = 0; t < nk; t++) {
    float p = expf(sv[t] - lmax);
    lsum += p;
    const float* vp = SQKV + ((long)(b * PQ + kks[t])) * 384 + 256 + h * 16;
#pragma unroll
    for (int d = 0; d < 16; d++) acc[d] = fmaf(p, vp[d], acc[d]);
  }
#pragma unroll
  for (int o = 32; o; o >>= 1) lsum += __shfl_xor(lsum, o, 64);
#pragma unroll
  for (int d = 0; d < 16; d++) {
    float v = acc[d];
#pragma unroll
    for (int o = 32; o; o >>= 1) v += __shfl_xor(v, o, 64);
    if (lane == 0) SAO[((long)(b * PQ + q)) * HIDDEN + h * 16 + d] = v / lsum;
  }
}

// ---------------------------------------------------------------------------
// MFMA flash cross-attention, key-split (R11 structure kept).
// ---------------------------------------------------------------------------
__global__ __launch_bounds__(256) void flash_mfma_k(const float* __restrict__ QH,
                                                    const bf16* __restrict__ KVT,
                                                    float* __restrict__ PART)
{
  __shared__ __align__(16) short Qs[64 * 40];      // [q][d] d in [16,32) zero
  __shared__ __align__(16) short Ks[2][32 * 40];   // [key][d] d in [16,32) zero
  __shared__ __align__(16) short Vs[2][16 * 40];   // [d][key]
  __shared__ __align__(16) short Ps[4][16 * 40];   // per-wave [q][key]
  int s = blockIdx.x, h = blockIdx.y;
  int b = blockIdx.z >> 2, qb = blockIdx.z & 3;
  int tid = threadIdx.x;
  int w = tid >> 6, lane = tid & 63;
  int lane15 = lane & 15, lgrp = lane >> 4;
  const short* Kb = (const short*)KVT + ((long)b * 256 + h * 16) * HW;
  const short* Vb = Kb + (long)128 * HW;
  int nbeg = s * SPLITLEN;

  // zero the d=[16,32) pad of both K buffers (disjoint from staged d<16)
  for (int e = tid; e < 2 * 32 * 16; e += 256) {
    int buf = e >> 9, rr = e & 511;
    int kk = rr >> 4, d2 = rr & 15;
    Ks[buf][kk * 40 + 16 + d2] = 0;
  }
  // stage Q once: q = tid>>2 (0..63), dgroup = tid&3 -> short8 at [q][dg*8]
  {
    int q = tid >> 2, dg = tid & 3;
    int gq = qb * 64 + q;
    short8 v = {};
    if (dg < 2 && gq < PQ) {
      const float* qp = QH + ((long)(b * PQ + gq)) * HIDDEN + h * 16 + dg * 8;
#pragma unroll
      for (int j = 0; j < 8; j++) v[j] = f2bf_bits(qp[j] * 0.25f);
    }
    *(short8*)&Qs[q * 40 + dg * 8] = v;
  }

  auto stageKV = [&](int t, int buf) {
    int kb0 = nbeg + t * CHK;
    for (int e = tid; e < 512; e += 256) {
      int d = e >> 5, kk = e & 31;
      long gk = kb0 + kk; if (gk >= HW) gk = HW - 1;   // clamped; masked later
      long go = (long)d * HW + gk;
      Ks[buf][kk * 40 + d] = Kb[go];
      Vs[buf][d * 40 + kk] = Vb[go];
    }
  };

  stageKV(0, 0);
  __syncthreads();

  short8 aq = *(const short8*)&Qs[(w * 16 + lane15) * 40 + lgrp * 8];
  float m[4] = {-1e30f, -1e30f, -1e30f, -1e30f};
  float l[4] = {0.f, 0.f, 0.f, 0.f};
  f32x4 accO = {};
  const int NTL = (SPLITLEN + CHK - 1) / CHK;  // 23 (last chunk 16 valid)
  for (int t = 0; t < NTL; t++) {
    int cur = t & 1;
    if (t + 1 < NTL) stageKV(t + 1, cur ^ 1);
    int valid = SPLITLEN - t * CHK; if (valid > CHK) valid = CHK;
    short8 bk0 = *(const short8*)&Ks[cur][lane15 * 40 + lgrp * 8];
    short8 bk1 = *(const short8*)&Ks[cur][(16 + lane15) * 40 + lgrp * 8];
    f32x4 z = {};
    f32x4 s0 = __builtin_amdgcn_mfma_f32_16x16x32_bf16(aq, bk0, z, 0, 0, 0);
    f32x4 s1 = __builtin_amdgcn_mfma_f32_16x16x32_bf16(aq, bk1, z, 0, 0, 0);
    bool msk0 = (lane15 >= valid);
    bool msk1 = (16 + lane15 >= valid);
#pragma unroll
    for (int r = 0; r < 4; r++) {
      float x0 = msk0 ? -1e30f : s0[r];
      float x1 = msk1 ? -1e30f : s1[r];
      float mx = fmaxf(x0, x1);
      mx = fmaxf(mx, __shfl_xor(mx, 1, 64));
      mx = fmaxf(mx, __shfl_xor(mx, 2, 64));
      mx = fmaxf(mx, __shfl_xor(mx, 4, 64));
      mx = fmaxf(mx, __shfl_xor(mx, 8, 64));
      float mn = fmaxf(m[r], mx);
      float p0 = exp2f((x0 - mn) * L2E);
      float p1 = exp2f((x1 - mn) * L2E);
      float sum = p0 + p1;
      sum += __shfl_xor(sum, 1, 64);
      sum += __shfl_xor(sum, 2, 64);
      sum += __shfl_xor(sum, 4, 64);
      sum += __shfl_xor(sum, 8, 64);
      float al = exp2f((m[r] - mn) * L2E);
      l[r] = l[r] * al + sum;
      m[r] = mn;
      accO[r] *= al;
      Ps[w][(lgrp * 4 + r) * 40 + lane15] = f2bf_bits(p0);
      Ps[w][(lgrp * 4 + r) * 40 + 16 + lane15] = f2bf_bits(p1);
    }
    short8 ap = *(const short8*)&Ps[w][lane15 * 40 + lgrp * 8];
    short8 bv = *(const short8*)&Vs[cur][lane15 * 40 + lgrp * 8];
    accO = __builtin_amdgcn_mfma_f32_16x16x32_bf16(ap, bv, accO, 0, 0, 0);
    __syncthreads();
  }
  long base = ((((long)(b * 8 + h)) * NSPLIT + s) * PQ) * 18;
#pragma unroll
  for (int r = 0; r < 4; r++) {
    int gq = qb * 64 + w * 16 + lgrp * 4 + r;
    if (gq < PQ) {
      long ro = base + (long)gq * 18;
      PART[ro + lane15] = accO[r];
      if (lane15 == 0) { PART[ro + 16] = m[r]; PART[ro + 17] = l[r]; }
    }
  }
}

__global__ void combine_k(const float* __restrict__ PART, float* __restrict__ CAO)
{
  int t = blockIdx.x * 256 + threadIdx.x;
  if (t >= 2 * 8 * PQ * 16) return;
  int d = t & 15; int r = t >> 4;
  int q = r % PQ; r /= PQ;
  int h = r & 7; int b = r >> 3;
  long base = (((long)(b * 8 + h)) * NSPLIT) * PQ * 18 + (long)q * 18;
  float M = -1e30f;
  for (int s = 0; s < NSPLIT; s++) M = fmaxf(M, PART[base + (long)s * PQ * 18 + 16]);
  float L = 0.f, O = 0.f;
  for (int s = 0; s < NSPLIT; s++) {
    long p0 = base + (long)s * PQ * 18;
    float w = expf(PART[p0 + 16] - M);
    L += PART[p0 + 17] * w;
    O += PART[p0 + d] * w;
  }
  CAO[((long)(b * PQ + q)) * HIDDEN + h * 16 + d] = (L > 0.f) ? O / L : 0.f;
}

__global__ __launch_bounds__(256) void ln_k(const float* __restrict__ PRE,
                                            const float* __restrict__ g,
                                            const float* __restrict__ bta,
                                            float* __restrict__ X)
{
  int row = blockIdx.x * 4 + (threadIdx.x >> 6);
  int lane = threadIdx.x & 63;
  const float* p = PRE + (long)row * HIDDEN;
  float v0 = p[lane], v1 = p[lane + 64];
  float s = v0 + v1;
#pragma unroll
  for (int o = 32; o; o >>= 1) s += __shfl_xor(s, o, 64);
  float mu = s * (1.f / 128.f);
  float d0 = v0 - mu, d1 = v1 - mu;
  float vs = d0 * d0 + d1 * d1;
#pragma unroll
  for (int o = 32; o; o >>= 1) vs += __shfl_xor(vs, o, 64);
  float rs = rsqrtf(vs * (1.f / 128.f) + 1e-5f);
  float* xo = X + (long)row * HIDDEN;
  xo[lane] = d0 * rs * g[lane] + bta[lane];
  xo[lane + 64] = d1 * rs * g[lane + 64] + bta[lane + 64];
}

__global__ __launch_bounds__(128) void conv1d_k(const float* __restrict__ X,
                                                const float* __restrict__ w,
                                                const float* __restrict__ bias,
                                                const float* __restrict__ g,
                                                const float* __restrict__ beta,
                                                float* __restrict__ Y)
{
  int p = blockIdx.x, b = blockIdx.y;
  int co = threadIdx.x;
  __shared__ float xs[3][HIDDEN];
  for (int e = co; e < 3 * HIDDEN; e += HIDDEN) {
    int t = e >> 7, c = e & 127;
    int pp = p + t - 1;
    xs[t][c] = (pp >= 0 && pp < PQ) ? X[((long)(b * PQ + pp)) * HIDDEN + c] : 0.f;
  }
  __syncthreads();
  const float* wr = w + (long)co * HIDDEN * 3;
  float acc = 0.f;
  for (int c = 0; c < HIDDEN; c++) {
    acc = fmaf(xs[0][c], wr[c * 3 + 0], acc);
    acc = fmaf(xs[1][c], wr[c * 3 + 1], acc);
    acc = fmaf(xs[2][c], wr[c * 3 + 2], acc);
  }
  float v = (acc + bias[co]) * g[co] + beta[co];
  Y[((long)(b * PQ + p)) * HIDDEN + co] = fmaxf(v, 0.f);
}

__global__ void head2_k(const float* __restrict__ Y, const float* __restrict__ w,
                        const float* __restrict__ bias, const float* __restrict__ qpos,
                        float* __restrict__ OUT, int N, float* __restrict__ qnext)
{
  int t = blockIdx.x * 256 + threadIdx.x;
  if (t >= 2 * N * PQ) return;
  int p = t % PQ; int r = t / PQ; int co = r % N; int b = r / N;
  const float* wr = w + (long)co * HIDDEN * 3;
  float acc = 0.f;
  for (int tap = 0; tap < 3; tap++) {
    int pp = p + tap - 1;
    if (pp < 0 || pp >= PQ) continue;
    const float* yr = Y + ((long)(b * PQ + pp)) * HIDDEN;
    for (int c = 0; c < HIDDEN; c++)
      acc = fmaf(yr[c], wr[c * 3 + tap], acc);
  }
  float v = acc + bias[co];
  if (qpos) v += qpos[((long)(b * PQ + p)) * 2 + co];
  OUT[((long)(b * N + co)) * PQ + p] = v;
  if (qnext) qnext[((long)(b * PQ + p)) * 2 + co] = v;
}

__global__ void out_k(const float* __restrict__ CENT, const float* __restrict__ HMP,
                      void* __restrict__ out, const unsigned* __restrict__ FLAGS)
{
  int t = blockIdx.x * 256 + threadIdx.x;
  if (t >= 2 * 12 * PQ) return;
  int p = t % PQ; int r = t / PQ; int ch = r % 12; int b = r / 12;
  float v = (ch < 2) ? CENT[((long)(b * 2 + ch)) * PQ + p]
                     : HMP[((long)(b * 10 + ch - 2)) * PQ + p];
  if (FLAGS[0]) ((bf16*)out)[t] = __float2bfloat16(v);
  else          ((float*)out)[t] = v;
}

// ---------------------------------------------------------------------------
extern "C" void kernel_launch(void* const* d_in, const int* in_sizes, int n_in,
                              void* d_out, int out_size, void* d_ws, size_t ws_size,
                              hipStream_t stream)
{
  (void)n_in; (void)out_size; (void)ws_size;

  // ---- workspace layout (~80 MB == validated watermark) -------------------
  float* F = (float*)d_ws;
  size_t off = 0;
  int aoff[42];
  {
    size_t acc = 0;
    for (int i = 2; i < 42; i++) { aoff[i] = (int)acc; acc += (size_t)in_sizes[i]; }
    off = acc;
  }
  float* ARENA = F;
  float* LIDF = F + off;                        // [2][128][HW] fp32 (dead after gather)
  bf16*  KVT16 = (bf16*)(F + off);              // alias: [2][256][HW] bf16 (decoder)
  off += 8294400;
  float* HBUF = F + off;                        // fp32 [1][128][HW] (fp32-mode hm)
  bf16*  HBUF2B = (bf16*)(F + off);             // alias: bf16 [2][128][HW] (bf16-mode hm)
  bf16*  KPET16 = (bf16*)(F + off);             // alias: [128][HW] bf16 (decoder)
  float* PART  = F + off;                       // alias: [2][8][NSPLIT][200][18]
  off += 4147200;
  bf16*  CAMF16 = (bf16*)(F + off);             // [2][128][HW] bf16 (live all run)
  off += 4147200;
  float* HEAT  = F + off;                       // [2][10][HW] (dead after nms)
  float* SCORE = F + off + 648000;              // (dead after collect)
  off += 1296000;
  float* X   = F + off; off += 51200;           // decoder smalls — all dead during
  float* XQ  = F + off; off += 51200;           // convs; WB_* aliases this region
  float* QPE = F + off; off += 51200;
  float* T1Q = F + off; off += 51200;
  float* SQKV = F + off; off += 153600;
  float* SAO = F + off; off += 51200;
  float* PRE = F + off; off += 51200;
  float* QH2 = F + off; off += 51200;
  float* CAO = F + off; off += 51200;
  float* FF1 = F + off; off += 102400;
  float* YC  = F + off; off += 51200;           // X..YC span = 716800 floats
  float* CENT = F + off; off += 800;
  float* HMP = F + off; off += 4000;
  float* QPA = F + off; off += 800;
  float* QPB = F + off; off += 800;
  unsigned* U = (unsigned*)(F + off);
  unsigned* HIST  = U;                          // [0, 8192)
  unsigned* ACNT  = U + 8192;                   // 2
  unsigned* THR   = U + 8194;                   // 2
  unsigned* FLAGS = U + 8196;                   // 2 (NOT zeroed by zero_u32)
  unsigned* TOPC  = U + 8198;                   // 400
  unsigned* TOPI  = U + 8598;                   // 400
  unsigned long long* CAND = (unsigned long long*)(U + 9000); // 2*CAP u64
  // 16-bit MFMA weight planes: alias the decoder-smalls region (dead during
  // wprep + convs). 1,327,104 shorts = 663,552 floats fits 716,800-float span.
  short* WB_LID = (short*)((((uintptr_t)X) + 15) & ~(uintptr_t)15);
  short* WB_CAM = WB_LID + 884736;              // 2*9*12*8*512 = 884736
  short* WB_HM1 = WB_CAM + 110592;              // 1*9*3*8*512  = 110592
  short* WB_HM2 = WB_HM1 + 294912;              // 2*9*4*8*512  = 294912 (+36864)

  auto W = [&](int i) -> const float* { return ARENA + aoff[i]; };

  // ---- dtype detect + weight conversion -----------------------------------
  detect_k<<<1, 256, 0, stream>>>((const unsigned*)d_in[0], FLAGS);
  {
    CvtArgs a;
    for (int i = 2; i < 42; i++) { a.src[i - 2] = d_in[i]; a.n[i - 2] = in_sizes[i]; a.off[i - 2] = aoff[i]; }
    cvt_k<<<dim3(432, 40), 256, 0, stream>>>(a, ARENA, FLAGS);
  }
  // dynamic planes: bf16 bits when FLAGS=1, fp16 split else (now ALL convs)
  wprep_k<<<3456, 256, 0, stream>>>(W(2), WB_LID, 128, 384, 12, 8, 1, FLAGS, 1);
  wprep_k<<<432, 256, 0, stream>>>(W(4), WB_CAM, 128, 80, 3, 8, 0, FLAGS, 1);
  wprep_k<<<1152, 256, 0, stream>>>(W(6), WB_HM1, 128, 128, 4, 8, 1, FLAGS, 1);
  wprep_k<<<144, 256, 0, stream>>>(W(10), WB_HM2, 10, 128, 4, 1, 1, FLAGS, 1);

  auto gemm = [&](const float* A, const float* A2, int lda, const float* Wp,
                  const float* bias, int act, const float* res, float* C, int ldc,
                  int M, int N, int K) {
    dim3 grid((M + 63) / 64, (N + 63) / 64, 1);
    gemm_k<float, float><<<grid, 256, 0, stream>>>(
        A, A2, lda, 0, 0L, Wp, bias, act, res,
        nullptr, nullptr, nullptr, nullptr, C, ldc, 0, 0L, M, N, K);
  };

  // ---- backbone convs (R2 geometry, inline staging, dual-gated) -----------
  conv_mfma<1, 1, 4, 4, 2, 60, float><<<dim3(544, 1, 2), 256, 0, stream>>>(
      d_in[0], FLAGS, 1, 1, (long)384 * HW, WB_LID, W(3), nullptr, nullptr, 0,
      LIDF, (long)128 * HW, 128, 384, 12, 8);
  conv_mfma<3, 1, 4, 4, 2, 60, float><<<dim3(544, 1, 2), 256, 0, stream>>>(
      d_in[0], FLAGS, 1, 0, (long)384 * HW, WB_LID, W(3), nullptr, nullptr, 0,
      LIDF, (long)128 * HW, 128, 384, 12, 8);
  conv_mfma<1, 1, 4, 4, 2, 60, bf16><<<dim3(544, 1, 2), 256, 0, stream>>>(
      d_in[1], FLAGS, 1, 1, (long)80 * HW, WB_CAM, W(5), nullptr, nullptr, 0,
      CAMF16, (long)128 * HW, 128, 80, 3, 8);
  conv_mfma<0, 1, 4, 4, 2, 60, bf16><<<dim3(544, 1, 2), 256, 0, stream>>>(
      d_in[1], FLAGS, 1, 0, (long)80 * HW, WB_CAM, W(5), nullptr, nullptr, 0,
      CAMF16, (long)128 * HW, 128, 80, 3, 8);
  // hm path, bf16 mode (gate=1): merged z=2, bf16 h-buffer (matches the
  // reference's own bf16 tensors; round(LIDF)->bf16 == reference lidar_feat).
  conv_mfma<2, 1, 4, 4, 2, 60, bf16><<<dim3(544, 1, 2), 256, 0, stream>>>(
      LIDF, FLAGS, 0, 1, (long)128 * HW, WB_HM1, W(7), W(8), W(9), 1,
      HBUF2B, (long)128 * HW, 128, 128, 4, 8);
  conv_mfma<1, 4, 1, 1, 1, 60, float><<<dim3(544, 1, 2), 256, 0, stream>>>(
      HBUF2B, FLAGS, 0, 1, (long)128 * HW, WB_HM2, W(11), nullptr, nullptr, 2,
      HEAT, (long)NCLS * HW, 10, 128, 4, 1);
  // hm path, fp32 mode (gate=0): exact fp16-split, per-batch fp32 HBUF.
  for (int b = 0; b < 2; b++) {
    conv_mfma<3, 1, 4, 4, 2, 60, float><<<dim3(544, 1, 1), 256, 0, stream>>>(
        LIDF + (long)b * 128 * HW, FLAGS, 0, 0, 0L, WB_HM1, W(7), W(8), W(9), 1,
        HBUF, 0L, 128, 128, 4, 8);
    conv_mfma<3, 4, 1, 1, 1, 60, float><<<dim3(544, 1, 1), 256, 0, stream>>>(
        HBUF, FLAGS, 0, 0, 0L, WB_HM2, W(11), nullptr, nullptr, 2,
        HEAT + (long)b * NCLS * HW, 0L, 10, 128, 4, 1);
  }

  // ---- NMS + exact top-200 ------------------------------------------------
  nms_k<<<(2 * NCLS * HW + 255) / 256, 256, 0, stream>>>(HEAT, SCORE);
  zero_u32<<<(8196 + 255) / 256, 256, 0, stream>>>(U, 8196);
  hist_k<<<dim3(240, 2), 256, 0, stream>>>(SCORE, HIST);
  thresh_k<<<2, 256, 0, stream>>>(HIST, THR);
  collect_k<<<(2 * NCLS * HW + 255) / 256, 256, 0, stream>>>(SCORE, THR, ACNT, CAND);
  select_k<<<2, 64, 0, stream>>>(CAND, ACNT, TOPC, TOPI, QPA);
  gather_k<<<200, 256, 0, stream>>>(LIDF, TOPC, TOPI, W(12), W(13), X);

  // ---- decoder layers -----------------------------------------------------
  for (int i = 0; i < 2; i++) {
    const float* qcur = (i == 0) ? QPA : QPB;
    float* qnext = (i == 0) ? QPB : QPA;
    // query pos-embed fused into GEMM staging (amode 3, A = qpos)
    gemm_k<float, float><<<dim3(7, 2, 1), 256, 0, stream>>>(
        qcur, (const float*)nullptr, 0, 3, 0L,
        W(18) + (size_t)(i * 2 + 0) * 16384, W(19) + (i * 2 + 0) * 128, 0, nullptr,
        W(14) + (i * 2 + 0) * 256, W(15) + (i * 2 + 0) * 128,
        W(16) + (i * 2 + 0) * 128, W(17) + (i * 2 + 0) * 128,
        QPE, 128, 0, 0L, 400, 128, 128);
    // key pos-embed (BEV grid fused), bf16 MFMA, stored transposed [128][HW]
    kpe_mfma_k<<<dim3(507, 2), 256, 0, stream>>>(
        W(14) + (i * 2 + 1) * 256, W(15) + (i * 2 + 1) * 128,
        W(16) + (i * 2 + 1) * 128, W(17) + (i * 2 + 1) * 128,
        W(18) + (size_t)(i * 2 + 1) * 16384, W(19) + (i * 2 + 1) * 128,
        KPET16);
    // self-attention (X+QPE fused via A2)
    gemm(X, QPE, 128, W(20) + (size_t)(i * 2 + 0) * 49152, W(21) + (i * 2 + 0) * 384,
         0, nullptr, SQKV, 384, 400, 384, 128);
    self_attn_k<<<dim3(200, 8, 2), 64, 0, stream>>>(SQKV, SAO);
    gemm(SAO, nullptr, 128, W(22) + (size_t)(i * 2 + 0) * 16384, W(23) + (i * 2 + 0) * 128,
         0, X, PRE, 128, 400, 128, 128);
    ln_k<<<100, 256, 0, stream>>>(PRE, W(24) + (i * 3 + 0) * 128, W(25) + (i * 3 + 0) * 128, X);
    // cross-attention Q projection (X+QPE fused via A2) — N=128 (Q rows only)
    gemm(X, QPE, 128, W(20) + (size_t)(i * 2 + 1) * 49152, W(21) + (i * 2 + 1) * 384,
         0, nullptr, QH2, 128, 400, 128, 128);
    kvproj_k<<<dim3(507, 2, 2), 256, 0, stream>>>(
        CAMF16, KPET16,
        W(20) + (size_t)(i * 2 + 1) * 49152 + 16384,
        W(21) + (i * 2 + 1) * 384 + 128, KVT16);
    flash_mfma_k<<<dim3(NSPLIT, 8, 8), 256, 0, stream>>>(QH2, KVT16, PART);
    combine_k<<<200, 256, 0, stream>>>(PART, CAO);
    gemm(CAO, nullptr, 128, W(22) + (size_t)(i * 2 + 1) * 16384, W(23) + (i * 2 + 1) * 128,
         0, X, PRE, 128, 400, 128, 128);
    ln_k<<<100, 256, 0, stream>>>(PRE, W(24) + (i * 3 + 1) * 128, W(25) + (i * 3 + 1) * 128, X);
    // FFN
    gemm(X, nullptr, 128, W(26) + (size_t)i * 32768, W(27) + i * 256,
         1, nullptr, FF1, 256, 400, 256, 128);
    gemm(FF1, nullptr, 256, W(28) + (size_t)i * 32768, W(29) + i * 128,
         0, X, PRE, 128, 400, 128, 256);
    ln_k<<<100, 256, 0, stream>>>(PRE, W(24) + (i * 3 + 2) * 128, W(25) + (i * 3 + 2) * 128, X);
    // prediction heads
    conv1d_k<<<dim3(200, 2), 128, 0, stream>>>(X, W(30) + (size_t)i * 49152,
        W(31) + i * 128, W(32) + i * 128, W(33) + i * 128, YC);
    head2_k<<<4, 256, 0, stream>>>(YC, W(34) + (size_t)i * 768, W(35) + i * 2,
        qcur, CENT, 2, qnext);
    conv1d_k<<<dim3(200, 2), 128, 0, stream>>>(X, W(36) + (size_t)i * 49152,
        W(37) + i * 128, W(38) + i * 128, W(39) + i * 128, YC);
    head2_k<<<16, 256, 0, stream>>>(YC, W(40) + (size_t)i * 3840, W(41) + i * 10,
        nullptr, HMP, 10, nullptr);
  }
  out_k<<<19, 256, 0, stream>>>(CENT, HMP, d_out, FLAGS);
}

// Round 8
// 1879.493 us; speedup vs baseline: 1.2162x; 1.0187x over previous
//
#include <hip/hip_runtime.h>
#include <hip/hip_bf16.h>

typedef __hip_bfloat16 bf16;
typedef _Float16 f16;

#define HW 32400
#define NCLS 10
#define PQ 200
#define HIDDEN 128
#define NSPLIT 45
#define SPLITLEN 720    // 45*720 = 32400 exactly
#define CHK 32
#define CAP 6144
#define NBIN 4096
#define L2E 1.44269504f

typedef __attribute__((ext_vector_type(8))) _Float16 half8;
typedef __attribute__((ext_vector_type(8))) short short8;
typedef __attribute__((ext_vector_type(4))) short short4v;
typedef __attribute__((ext_vector_type(4))) float f32x4;

__device__ __forceinline__ float b2f(bf16 v) { return __bfloat162float(v); }
__device__ __forceinline__ void stf(float* p, float v) { *p = v; }
__device__ __forceinline__ void stf(bf16* p, float v) { *p = __float2bfloat16(v); }
// runtime-dtype load: isbf!=0 -> bf16 array, else fp32 array
__device__ __forceinline__ float ldsel(const void* p, long i, unsigned isbf) {
  return isbf ? __bfloat162float(((const bf16*)p)[i]) : ((const float*)p)[i];
}
__device__ __forceinline__ float ldf(const float* p, long i) { return p[i]; }
__device__ __forceinline__ float ldf(const bf16* p, long i) { return __bfloat162float(p[i]); }
__device__ __forceinline__ short f2bf_bits(float v) {
  union { bf16 h; short s; } u; u.h = __float2bfloat16(v); return u.s;
}
__device__ __forceinline__ short f2h_bits(float v) {
  union { f16 h; short s; } u; u.h = (f16)v; return u.s;
}

// ---------------------------------------------------------------------------
// dtype detection (bf16 vs fp32 inputs) -> FLAGS[0]
// NOTE (R17): this bench's input IS fp32 (FLAGS=0) — evidence: the running
// conv dispatches show LDS 31744 = MODE-3 dual-plane layout; in_npz ~116MB
// matches fp32. The fp32 (gate=0) path is the hot path; bf16 kernels are
// kept for robustness but are cold here.
// ---------------------------------------------------------------------------
__global__ void detect_k(const unsigned* __restrict__ L, unsigned* __restrict__ FLAGS)
{
  __shared__ unsigned cnt[2];
  int tid = threadIdx.x;
  if (tid < 2) cnt[tid] = 0;
  __syncthreads();
  unsigned nz = 0, pl = 0;
  for (int w = tid; w < 4096; w += 256) {
    unsigned u = L[w];
    if (u) {
      nz++;
      unsigned e = (u >> 7) & 0xFF;
      if (e >= 110 && e <= 140) pl++;
    }
  }
  atomicAdd(&cnt[0], nz);
  atomicAdd(&cnt[1], pl);
  __syncthreads();
  if (tid == 0) {
    FLAGS[0] = (2u * cnt[1] > cnt[0]) ? 1u : 0u;
    FLAGS[1] = 0u;
  }
}

// batched weight conversion into fp32 arena (exact in both modes)
struct CvtArgs { const void* src[40]; int n[40]; int off[40]; };
__global__ __launch_bounds__(256) void cvt_k(CvtArgs a, float* __restrict__ dst,
                                             const unsigned* __restrict__ FLAGS)
{
  int j = blockIdx.y;
  unsigned isbf = FLAGS[0];
  int n = a.n[j];
  const void* s = a.src[j];
  float* d = dst + a.off[j];
  for (int t = blockIdx.x * 256 + threadIdx.x; t < n; t += gridDim.x * 256)
    d[t] = ldsel(s, t, isbf);
}

// ---------------------------------------------------------------------------
// Conv weight pre-swizzle into MFMA fragment order (16-bit planes).
// WB[plane][tap][kb][nt][n16][k32] ; value = W[nt*16+n16][kb*32+k][ty][tx]
// dynmode=1 and FLAGS[0]=1 (bf16 weights): plane0 = bf16 bits (exact), p1=0.
// else: plane0 = fp16 hi, plane1 = fp16((v - hi) * 4096)  (fp32-split).
// ---------------------------------------------------------------------------
__global__ __launch_bounds__(256) void wprep_k(const float* __restrict__ Wsrc,
    short* __restrict__ WB, int N, int K, int KB, int NTG, int split,
    const unsigned* __restrict__ FLAGS, int dynmode)
{
  unsigned isbf = dynmode ? FLAGS[0] : 0u;
  long total = (long)(split ? 2 : 1) * 9 * KB * NTG * 512;
  for (long t = (long)blockIdx.x * 256 + threadIdx.x; t < total;
       t += (long)gridDim.x * 256) {
    long r = t;
    int k = (int)(r & 31); r >>= 5;
    int n16 = (int)(r & 15); r >>= 4;
    int nt = (int)(r % NTG); r /= NTG;
    int kb = (int)(r % KB); r /= KB;
    int tap = (int)(r % 9); r /= 9;
    int plane = (int)r;
    int n = nt * 16 + n16, kk = kb * 32 + k;
    float v = 0.f;
    if (n < N && kk < K) v = Wsrc[((long)n * K + kk) * 9 + tap];
    short outv;
    if (isbf) {
      outv = (plane == 0) ? f2bf_bits(v) : (short)0;
    } else {
      f16 h = (f16)v;
      if (plane == 0) outv = f2h_bits((float)h);
      else outv = f2h_bits((v - (float)h) * 4096.0f);
    }
    WB[t] = outv;
  }
}

// ---------------------------------------------------------------------------
// MFMA conv2d 3x3 SAME as 9 shifted GEMMs over CW-pixel row chunks.
// MODE 3: fp32-accurate fp16 split (3 MFMAs).  MODE 0: plain fp16.
// MODE 1: exact bf16 (input already bf16: raw-bit staging, 1 bf16 MFMA).
// MODE 2: fp32 input rounded to bf16 (1 bf16 MFMA; bf16-mode hm path).
// gate: -1 always run; 0/1 run only when FLAGS[0] matches (dual-launch).
// STAGING = R2/R14 inline loop, VGPR ~76. LEDGER (do not retry): R12 CW=30
// (more phases, slower); R13 reg-prefetch & R15 batched staging (both +80
// VGPR -> occupancy 10%, ~2.2x slower). Any scheme holding a kb-tile in
// registers pays the VGPR peak; the inline loop is the local optimum.
// ---------------------------------------------------------------------------
template <int MODE, int WM, int WN, int MT, int NT, int CW, typename CT>
__global__ __launch_bounds__(256) void conv_mfma(
    const void* __restrict__ A, const unsigned* __restrict__ FLAGS, int dyn,
    int gate, long abatch,
    const short* __restrict__ WB, const float* __restrict__ bias,
    const float* __restrict__ g, const float* __restrict__ beta, int act,
    CT* __restrict__ C, long cbatch, int N, int K, int KB, int NTG)
{
  constexpr bool BF = (MODE == 1 || MODE == 2);
  constexpr int CPR = 180 / CW;              // chunks per row
  constexpr int TOT = 180 * CPR;             // total chunks
  constexpr int BAND = (TOT + 7) / 8;        // chunks per XCD band
  constexpr int PXS = WM * MT * 16 + 2;      // staged px per row (+2 halo)
  constexpr int AW = 3 * PXS * 40;           // [ty][px][k] k-stride 40 (shorts)
  __shared__ __align__(16) short Ah[AW];
  __shared__ __align__(16) short Al[MODE == 3 ? AW : 8];
  if (gate >= 0 && FLAGS[0] != (unsigned)gate) return;
  // XCD band swizzle: idx = (g&7)*BAND + (g>>3)
  int gsw = blockIdx.x;
  int idx = (gsw & 7) * BAND + (gsw >> 3);
  if (idx >= TOT) return;
  unsigned isbf = dyn ? FLAGS[0] : 0u;
  int bz = blockIdx.z;
  int y = idx / CPR;
  int x0 = (idx % CPR) * CW;
  int tid = threadIdx.x;
  int w = tid >> 6, lane = tid & 63;
  int lane15 = lane & 15, lgrp = lane >> 4;
  int wm = w % WM, wn = w / WM;
  int mbase = wm * MT * 16;
  int nbase = wn * NT * 16;
  f32x4 accM[MT][NT] = {};
  f32x4 accC[MODE == 3 ? MT : 1][MODE == 3 ? NT : 1] = {};
  long planeStride = (long)9 * KB * NTG * 512;

  for (int kb = 0; kb < KB; kb++) {
    __syncthreads();
    // inline staging: 3 rows x PXS px x 4 k-groups of 8 (one short8 each)
    for (int u = tid; u < 3 * PXS * 4; u += 256) {
      int px = u % PXS;
      int t2 = u / PXS;
      int kg = t2 & 3, row = t2 >> 2;
      int gx = x0 + px - 1, gy = y + row - 1;
      bool in = (gx >= 0 && gx < 180 && gy >= 0 && gy < 180);
      long gbase = (long)bz * abatch + (long)(kb * 32 + kg * 8) * HW +
                   (long)gy * 180 + gx;
      short8 hv, lv;
#pragma unroll
      for (int j = 0; j < 8; j++) {
        int kk = kb * 32 + kg * 8 + j;
        if constexpr (MODE == 1) {
          // input already bf16: copy bits directly (exact)
          hv[j] = (in && kk < K) ? ((const short*)A)[gbase + (long)j * HW]
                                 : (short)0;
        } else if constexpr (MODE == 2) {
          // fp32 input rounded to bf16 (matches reference's bf16 tensor)
          float v = (in && kk < K) ? ((const float*)A)[gbase + (long)j * HW]
                                   : 0.f;
          hv[j] = f2bf_bits(v);
        } else {
          float v = (in && kk < K) ? ldsel(A, gbase + (long)j * HW, isbf) : 0.f;
          f16 h = (f16)v;
          hv[j] = f2h_bits((float)h);
          if constexpr (MODE == 3) lv[j] = f2h_bits((v - (float)h) * 4096.0f);
        }
      }
      int o = (row * PXS + px) * 40 + kg * 8;  // *2B: px-stride 80, 16B aligned
      *(short8*)&Ah[o] = hv;
      if constexpr (MODE == 3) *(short8*)&Al[o] = lv;
    }
    __syncthreads();
#pragma unroll
    for (int tap = 0; tap < 9; tap++) {
      int ty = tap / 3, tx = tap % 3;
      const short* wb = WB + (((long)tap * KB + kb) * NTG) * 512;
      if constexpr (BF) {
        short8 bh[NT];
#pragma unroll
        for (int nt = 0; nt < NT; nt++) {
          long o = (long)(wn * NT + nt) * 512 + lane15 * 32 + lgrp * 8;
          bh[nt] = *(const short8*)(wb + o);
        }
        short8 ah[MT];
#pragma unroll
        for (int mt = 0; mt < MT; mt++) {
          int px = mbase + mt * 16 + lane15 + tx;
          ah[mt] = *(const short8*)&Ah[(ty * PXS + px) * 40 + lgrp * 8];
        }
#pragma unroll
        for (int mt = 0; mt < MT; mt++)
#pragma unroll
          for (int nt = 0; nt < NT; nt++)
            accM[mt][nt] = __builtin_amdgcn_mfma_f32_16x16x32_bf16(
                ah[mt], bh[nt], accM[mt][nt], 0, 0, 0);
      } else {
        half8 bh[NT], bl[MODE == 3 ? NT : 1];
#pragma unroll
        for (int nt = 0; nt < NT; nt++) {
          long o = (long)(wn * NT + nt) * 512 + lane15 * 32 + lgrp * 8;
          bh[nt] = *(const half8*)(wb + o);
          if constexpr (MODE == 3) bl[nt] = *(const half8*)(wb + planeStride + o);
        }
        half8 ah[MT], al[MODE == 3 ? MT : 1];
#pragma unroll
        for (int mt = 0; mt < MT; mt++) {
          int px = mbase + mt * 16 + lane15 + tx;
          int o = (ty * PXS + px) * 40 + lgrp * 8;
          ah[mt] = *(const half8*)&Ah[o];
          if constexpr (MODE == 3) al[mt] = *(const half8*)&Al[o];
        }
#pragma unroll
        for (int mt = 0; mt < MT; mt++)
#pragma unroll
          for (int nt = 0; nt < NT; nt++) {
            accM[mt][nt] = __builtin_amdgcn_mfma_f32_16x16x32_f16(
                ah[mt], bh[nt], accM[mt][nt], 0, 0, 0);
            if constexpr (MODE == 3) {
              accC[mt][nt] = __builtin_amdgcn_mfma_f32_16x16x32_f16(
                  al[mt], bh[nt], accC[mt][nt], 0, 0, 0);
              accC[mt][nt] = __builtin_amdgcn_mfma_f32_16x16x32_f16(
                  ah[mt], bl[nt], accC[mt][nt], 0, 0, 0);
            }
          }
      }
    }
  }
  int pixbase = y * 180 + x0;
#pragma unroll
  for (int mt = 0; mt < MT; mt++) {
    int m = mbase + mt * 16 + lgrp * 4;
    if (m >= CW) continue;
#pragma unroll
    for (int nt = 0; nt < NT; nt++) {
      int n = nbase + nt * 16 + lane15;
      if (n >= N) continue;
      float bi = bias[n];
      float gg = g ? g[n] : 1.f;
      float bb = g ? beta[n] : 0.f;
      long base = (long)bz * cbatch + (long)n * HW + pixbase + m;
      float vv[4];
#pragma unroll
      for (int r = 0; r < 4; r++) {
        float v = accM[mt][nt][r];
        if constexpr (MODE == 3) v += accC[mt][nt][r] * (1.f / 4096.f);
        v += bi;
        if (g) v = v * gg + bb;
        if (act == 1) v = fmaxf(v, 0.f);
        else if (act == 2) v = 1.f / (1.f + expf(-v));
        vv[r] = v;
      }
      if constexpr (sizeof(CT) == 4) {
        if (m + 3 < CW) {
          f32x4 ov; ov[0] = vv[0]; ov[1] = vv[1]; ov[2] = vv[2]; ov[3] = vv[3];
          *(f32x4*)&C[base] = ov;
        } else {
#pragma unroll
          for (int r = 0; r < 4; r++) if (m + r < CW) C[base + r] = vv[r];
        }
      } else {
        if (m + 3 < CW) {
          short4v ov;
#pragma unroll
          for (int r = 0; r < 4; r++) ov[r] = f2bf_bits(vv[r]);
          *(short4v*)&C[base] = ov;
        } else {
#pragma unroll
          for (int r = 0; r < 4; r++)
            if (m + r < CW) *((short*)&C[base + r]) = f2bf_bits(vv[r]);
        }
      }
    }
  }
}

// ---------------------------------------------------------------------------
// bf16 MFMA KV projection: C = (A1+A2) @ W^T + bias.
// y-merged (R15): each block covers 128 of 256 output rows (NT=4, grid y=2).
// ---------------------------------------------------------------------------
__global__ __launch_bounds__(256) void kvproj_k(
    const bf16* __restrict__ A1, const bf16* __restrict__ A2,
    const float* __restrict__ Wf, const float* __restrict__ bias,
    bf16* __restrict__ C)
{
  __shared__ __align__(16) short As[64 * 40];
  int m0 = blockIdx.x * 64;
  int n0 = blockIdx.y * 128;
  int b = blockIdx.z;
  int tid = threadIdx.x;
  int w = tid >> 6, lane = tid & 63;
  int lane15 = lane & 15, lgrp = lane >> 4;
  int wm = w & 1, wn = w >> 1;
  const bf16* A1b = A1 + (long)b * 128 * HW;
  f32x4 acc[2][4] = {};
  for (int kb = 0; kb < 4; kb++) {
    __syncthreads();
    for (int e = tid; e < 2048; e += 256) {
      int k = e >> 6, m = e & 63;
      int gm = m0 + m;
      float v = 0.f;
      if (gm < HW) {
        long idx = (long)(kb * 32 + k) * HW + gm;
        v = b2f(A1b[idx]) + b2f(A2[idx]);
      }
      As[m * 40 + k] = f2bf_bits(v);
    }
    __syncthreads();
    short8 bh[4];
#pragma unroll
    for (int nt = 0; nt < 4; nt++) {
      int n = n0 + wn * 64 + nt * 16 + lane15;
      const float* wr = Wf + (long)n * 128 + kb * 32 + lgrp * 8;
      float4 w0 = *(const float4*)wr;
      float4 w1 = *(const float4*)(wr + 4);
      short8 t;
      t[0] = f2bf_bits(w0.x); t[1] = f2bf_bits(w0.y);
      t[2] = f2bf_bits(w0.z); t[3] = f2bf_bits(w0.w);
      t[4] = f2bf_bits(w1.x); t[5] = f2bf_bits(w1.y);
      t[6] = f2bf_bits(w1.z); t[7] = f2bf_bits(w1.w);
      bh[nt] = t;
    }
    short8 ah[2];
#pragma unroll
    for (int mt = 0; mt < 2; mt++) {
      int m = wm * 32 + mt * 16 + lane15;
      ah[mt] = *(const short8*)&As[m * 40 + lgrp * 8];
    }
#pragma unroll
    for (int mt = 0; mt < 2; mt++)
#pragma unroll
      for (int nt = 0; nt < 4; nt++)
        acc[mt][nt] = __builtin_amdgcn_mfma_f32_16x16x32_bf16(
            ah[mt], bh[nt], acc[mt][nt], 0, 0, 0);
  }
#pragma unroll
  for (int mt = 0; mt < 2; mt++) {
    int mq = m0 + wm * 32 + mt * 16 + lgrp * 4;
    if (mq >= HW) continue;
#pragma unroll
    for (int nt = 0; nt < 4; nt++) {
      int n = n0 + wn * 64 + nt * 16 + lane15;
      float bi = bias[n];
      short4v ov;
#pragma unroll
      for (int r = 0; r < 4; r++) ov[r] = f2bf_bits(acc[mt][nt][r] + bi);
      *(short4v*)&C[(long)b * 256 * HW + (long)n * HW + mq] = ov;
    }
  }
}

// ---------------------------------------------------------------------------
// bf16 MFMA KPE projection: KPET[n][m] = posembed_relu(m) @ W2^T + b2.
// ---------------------------------------------------------------------------
__global__ __launch_bounds__(256) void kpe_mfma_k(
    const float* __restrict__ pe1w, const float* __restrict__ pe1b,
    const float* __restrict__ pe1g, const float* __restrict__ pe1bt,
    const float* __restrict__ W2, const float* __restrict__ b2,
    bf16* __restrict__ C)
{
  __shared__ __align__(16) short As[64 * 40];
  int m0 = blockIdx.x * 64;
  int n0 = blockIdx.y * 64;
  int tid = threadIdx.x;
  int w = tid >> 6, lane = tid & 63;
  int lane15 = lane & 15, lgrp = lane >> 4;
  int wm = w & 1, wn = w >> 1;
  f32x4 acc[2][2] = {};
  for (int kb = 0; kb < 4; kb++) {
    __syncthreads();
    for (int e = tid; e < 2048; e += 256) {
      int k = e >> 6, m = e & 63;
      int gm = m0 + m;
      int kk = kb * 32 + k;
      float v = 0.f;
      if (gm < HW) {
        float p0 = (float)(gm / 180) + 0.5f;
        float p1 = (float)(gm % 180) + 0.5f;
        float t = p0 * pe1w[kk * 2] + p1 * pe1w[kk * 2 + 1] + pe1b[kk];
        t = t * pe1g[kk] + pe1bt[kk];
        v = fmaxf(t, 0.f);
      }
      As[m * 40 + k] = f2bf_bits(v);
    }
    __syncthreads();
    short8 bh[2];
#pragma unroll
    for (int nt = 0; nt < 2; nt++) {
      int n = n0 + wn * 32 + nt * 16 + lane15;
      const float* wr = W2 + (long)n * 128 + kb * 32 + lgrp * 8;
      float4 w0 = *(const float4*)wr;
      float4 w1 = *(const float4*)(wr + 4);
      short8 t;
      t[0] = f2bf_bits(w0.x); t[1] = f2bf_bits(w0.y);
      t[2] = f2bf_bits(w0.z); t[3] = f2bf_bits(w0.w);
      t[4] = f2bf_bits(w1.x); t[5] = f2bf_bits(w1.y);
      t[6] = f2bf_bits(w1.z); t[7] = f2bf_bits(w1.w);
      bh[nt] = t;
    }
    short8 ah[2];
#pragma unroll
    for (int mt = 0; mt < 2; mt++) {
      int m = wm * 32 + mt * 16 + lane15;
      ah[mt] = *(const short8*)&As[m * 40 + lgrp * 8];
    }
#pragma unroll
    for (int mt = 0; mt < 2; mt++)
#pragma unroll
      for (int nt = 0; nt < 2; nt++)
        acc[mt][nt] = __builtin_amdgcn_mfma_f32_16x16x32_bf16(
            ah[mt], bh[nt], acc[mt][nt], 0, 0, 0);
  }
#pragma unroll
  for (int mt = 0; mt < 2; mt++) {
    int mq = m0 + wm * 32 + mt * 16 + lgrp * 4;
    if (mq >= HW) continue;   // mq 4-aligned, HW%4==0 -> vector store safe
#pragma unroll
    for (int nt = 0; nt < 2; nt++) {
      int n = n0 + wn * 32 + nt * 16 + lane15;
      float bi = b2[n];
      short4v ov;
#pragma unroll
      for (int r = 0; r < 4; r++) ov[r] = f2bf_bits(acc[mt][nt][r] + bi);
      *(short4v*)&C[(long)n * HW + mq] = ov;
    }
  }
}

// ---------------------------------------------------------------------------
// Generic tiled GEMM: C = act((A [+A2]) @ W^T + bias) (+ res)
// amode 0: A[m*lda+k] (+A2 same layout).  amode 3: fused QUERY pos-embed.
// cmode 0: C[m*ldc+n] ; cmode 1: C[n*ldc+m].  K multiple of 16.
// ---------------------------------------------------------------------------
template <typename AT, typename CT>
__global__ __launch_bounds__(256) void gemm_k(
    const AT* __restrict__ A, const AT* __restrict__ A2, int lda, int amode,
    long abatch,
    const float* __restrict__ W, const float* __restrict__ bias, int act,
    const float* __restrict__ res,
    const float* __restrict__ pe1w, const float* __restrict__ pe1b,
    const float* __restrict__ pe1g, const float* __restrict__ pe1bt,
    CT* __restrict__ C, int ldc, int cmode, long cbatch,
    int M, int N, int K)
{
  __shared__ __align__(16) float As[16][68];
  __shared__ __align__(16) float Ws[16][68];
  int b = blockIdx.z;
  int m0 = blockIdx.x * 64, n0 = blockIdx.y * 64;
  int tid = threadIdx.x;
  int nt = tid & 15, mt = tid >> 4;
  float acc[4][4] = {};
  const AT* Ab = A + (long)b * abatch;
  for (int k0 = 0; k0 < K; k0 += 16) {
    if (amode == 0) {
      for (int e = tid; e < 1024; e += 256) {
        int m = e >> 4, k = e & 15;
        float v = 0.f;
        if (m0 + m < M) {
          long idx = (long)(m0 + m) * lda + k0 + k;
          v = ldf(Ab, idx);
          if (A2) v += ldf(A2, idx);
        }
        As[k][m] = v;
      }
    } else { // amode 3: query pos-embed, A = qpos (fp32 [M][2])
      const float* qp = (const float*)A;
      for (int e = tid; e < 1024; e += 256) {
        int m = e & 63, k = e >> 6;
        float v = 0.f;
        int gm = m0 + m;
        if (gm < M) {
          float p0 = qp[gm * 2], p1 = qp[gm * 2 + 1];
          int kk = k0 + k;
          float t = p0 * pe1w[kk * 2] + p1 * pe1w[kk * 2 + 1] + pe1b[kk];
          t = t * pe1g[kk] + pe1bt[kk];
          v = fmaxf(t, 0.f);
        }
        As[k][m] = v;
      }
    }
    for (int e = tid; e < 1024; e += 256) {
      int n = e >> 4, k = e & 15;
      float v = 0.f;
      if (n0 + n < N) v = W[(long)(n0 + n) * K + k0 + k];
      Ws[k][n] = v;
    }
    __syncthreads();
#pragma unroll
    for (int kk = 0; kk < 16; kk++) {
      float4 av = *(const float4*)&As[kk][mt * 4];
      float4 wv = *(const float4*)&Ws[kk][nt * 4];
      float am[4] = {av.x, av.y, av.z, av.w};
      float wn[4] = {wv.x, wv.y, wv.z, wv.w};
#pragma unroll
      for (int mi = 0; mi < 4; mi++)
#pragma unroll
        for (int ni = 0; ni < 4; ni++)
          acc[mi][ni] = fmaf(am[mi], wn[ni], acc[mi][ni]);
    }
    __syncthreads();
  }
#pragma unroll
  for (int mi = 0; mi < 4; mi++) {
    int m = m0 + mt * 4 + mi;
    if (m >= M) continue;
#pragma unroll
    for (int ni = 0; ni < 4; ni++) {
      int n = n0 + nt * 4 + ni;
      if (n >= N) continue;
      float v = acc[mi][ni];
      if (bias) v += bias[n];
      if (act == 1) v = fmaxf(v, 0.f);
      if (res) v += res[(long)m * ldc + n];
      long ci = (cmode == 0) ? ((long)b * cbatch + (long)m * ldc + n)
                             : ((long)b * cbatch + (long)n * ldc + m);
      stf(&C[ci], v);
    }
  }
}

// ---------------------------------------------------------------------------
__global__ void nms_k(const float* __restrict__ HEAT, float* __restrict__ SCORE)
{
  int t = blockIdx.x * 256 + threadIdx.x;
  if (t >= 2 * NCLS * HW) return;
  int b = t / (NCLS * HW); int r = t % (NCLS * HW);
  int cls = r / HW; int n = r % HW;
  const float* hb = HEAT + ((long)(b * NCLS + cls)) * HW;
  float v = hb[n];
  bool keep = true;
  if (cls < 8) {
    int y = n / 180, x = n % 180;
    if (y == 0 || y == 179 || x == 0 || x == 179) keep = false;
    else {
      float mx = -1e30f;
#pragma unroll
      for (int dy = -1; dy <= 1; dy++)
#pragma unroll
        for (int dx = -1; dx <= 1; dx++)
          mx = fmaxf(mx, hb[(y + dy) * 180 + x + dx]);
      keep = (v == mx);
    }
  }
  SCORE[(long)b * (NCLS * HW) + r] = keep ? v : 0.f;
}

__global__ void zero_u32(unsigned* p, int n)
{
  int t = blockIdx.x * 256 + threadIdx.x;
  if (t < n) p[t] = 0;
}

__global__ __launch_bounds__(256) void hist_k(const float* __restrict__ SCORE,
                                              unsigned* __restrict__ HIST)
{
  __shared__ unsigned lh[NBIN];
  int b = blockIdx.y;
  for (int e = threadIdx.x; e < NBIN; e += 256) lh[e] = 0;
  __syncthreads();
  int start = blockIdx.x * 1350;
  const float* sb = SCORE + (long)b * (NCLS * HW);
  for (int e = start + threadIdx.x; e < start + 1350; e += 256) {
    unsigned bits = __float_as_uint(sb[e]);
    atomicAdd(&lh[bits >> 18], 1u);
  }
  __syncthreads();
  for (int e = threadIdx.x; e < NBIN; e += 256) {
    unsigned c = lh[e];
    if (c) atomicAdd(&HIST[b * NBIN + e], c);
  }
}

__global__ void thresh_k(const unsigned* __restrict__ HIST, unsigned* __restrict__ THR)
{
  __shared__ unsigned ps[256];
  int b = blockIdx.x;
  const unsigned* hb = HIST + b * NBIN;
  unsigned s = 0;
  for (int j = 0; j < 16; j++) s += hb[threadIdx.x * 16 + j];
  ps[threadIdx.x] = s;
  __syncthreads();
  if (threadIdx.x == 0) {
    unsigned cum = 0; int t = 255;
    for (; t > 0; t--) { if (cum + ps[t] >= PQ) break; cum += ps[t]; }
    int bin = t * 16 + 15;
    for (; bin > t * 16; bin--) { unsigned c = hb[bin]; if (cum + c >= PQ) break; cum += c; }
    if (bin < 1) bin = 1;
    THR[b] = (unsigned)bin;
  }
}

__global__ void collect_k(const float* __restrict__ SCORE, const unsigned* __restrict__ THR,
                          unsigned* __restrict__ ACNT, unsigned long long* __restrict__ CAND)
{
  int t = blockIdx.x * 256 + threadIdx.x;
  if (t >= 2 * NCLS * HW) return;
  int b = t / (NCLS * HW); int r = t % (NCLS * HW);
  float v = SCORE[(long)b * (NCLS * HW) + r];
  unsigned bits = __float_as_uint(v);
  if ((bits >> 18) >= THR[b]) {
    unsigned slot = atomicAdd(&ACNT[b], 1u);
    if (slot < CAP) CAND[(long)b * CAP + slot] =
        ((unsigned long long)bits << 32) | (unsigned)(~r);
  }
}

__global__ __launch_bounds__(64) void select_k(
    const unsigned long long* __restrict__ CAND, const unsigned* __restrict__ ACNT,
    unsigned* __restrict__ TOPC, unsigned* __restrict__ TOPI, float* __restrict__ QPA)
{
  __shared__ unsigned long long cnd[CAP];
  int b = blockIdx.x;
  int lane = threadIdx.x;
  unsigned cnt = ACNT[b]; if (cnt > CAP) cnt = CAP;
  for (int e = lane; e < (int)cnt; e += 64) cnd[e] = CAND[(long)b * CAP + e];
  __syncthreads();
  for (int p = 0; p < PQ; p++) {
    unsigned long long best = 0;
    for (int e = lane; e < (int)cnt; e += 64) { unsigned long long c = cnd[e]; if (c > best) best = c; }
#pragma unroll
    for (int o = 32; o; o >>= 1) {
      unsigned long long other = __shfl_xor(best, o, 64);
      if (other > best) best = other;
    }
    for (int e = lane; e < (int)cnt; e += 64) if (best != 0 && cnd[e] == best) cnd[e] = 0;
    if (lane == 0) {
      unsigned idx = (best == 0) ? 0u : ~(unsigned)(best & 0xFFFFFFFFull);
      if (idx >= NCLS * HW) idx = 0;
      unsigned cls = idx / HW, n = idx % HW;
      TOPC[b * PQ + p] = cls; TOPI[b * PQ + p] = n;
      QPA[((long)(b * PQ + p)) * 2 + 0] = (float)(n / 180) + 0.5f;
      QPA[((long)(b * PQ + p)) * 2 + 1] = (float)(n % 180) + 0.5f;
    }
    __syncthreads();
  }
}

__global__ void gather_k(const float* __restrict__ LIDF, const unsigned* __restrict__ TOPC,
                         const unsigned* __restrict__ TOPI, const float* __restrict__ cew,
                         const float* __restrict__ ceb, float* __restrict__ X)
{
  int t = blockIdx.x * 256 + threadIdx.x;
  if (t >= 2 * PQ * HIDDEN) return;
  int c = t & 127; int r = t >> 7; int p = r % PQ; int b = r / PQ;
  unsigned n = TOPI[b * PQ + p]; unsigned cls = TOPC[b * PQ + p];
  if (n >= HW) n = 0;
  if (cls >= NCLS) cls = 0;
  X[t] = LIDF[((long)(b * HIDDEN + c)) * HW + n] + cew[c * NCLS + cls] + ceb[c];
}

__global__ __launch_bounds__(64) void self_attn_k(const float* __restrict__ SQKV,
                                                  float* __restrict__ SAO)
{
  int q = blockIdx.x, h = blockIdx.y, b = blockIdx.z;
  int lane = threadIdx.x;
  const float* qp = SQKV + ((long)(b * PQ + q)) * 384 + h * 16;
  float qv[16];
#pragma unroll
  for (int d = 0; d < 16; d++) qv[d] = qp[d] * 0.25f;
  float sv[4]; int kks[4]; int nk = 0;
  float lmax = -1e30f;
  for (int kk = lane; kk < PQ; kk += 64) {
    const float* kp = SQKV + ((long)(b * PQ + kk)) * 384 + 128 + h * 16;
    float s = 0.f;
#pragma unroll
    for (int d = 0; d < 16; d++) s = fmaf(qv[d], kp[d], s);
    sv[nk] = s; kks[nk] = kk; nk++;
    lmax = fmaxf(lmax, s);
  }
#pragma unroll
  for (int o = 32; o; o >>= 1) lmax = fmaxf(lmax, __shfl_xor(lmax, o, 64));
  float lsum = 0.f; float acc[16] = {};
  for (int t = 0; t < nk; t++) {
    float p = expf(sv[t] - lmax);
    lsum += p;
    const float* vp = SQKV + ((long)(b * PQ + kks[t])) * 384 + 256 + h * 16;
#pragma unroll
    for (int d = 0; d < 16; d++) acc[d] = fmaf(p, vp[d], acc[d]);
  }
#pragma unroll
  for (int o = 32; o; o >>= 1) lsum += __shfl_xor(lsum, o, 64);
#pragma unroll
  for (int d = 0; d < 16; d++) {
    float v = acc[d];
#pragma unroll
    for (int o = 32; o; o >>= 1) v += __shfl_xor(v, o, 64);
    if (lane == 0) SAO[((long)(b * PQ + q)) * HIDDEN + h * 16 + d] = v / lsum;
  }
}

// ---------------------------------------------------------------------------
// MFMA flash cross-attention, key-split (R11 structure kept).
// ---------------------------------------------------------------------------
__global__ __launch_bounds__(256) void flash_mfma_k(const float* __restrict__ QH,
                                                    const bf16* __restrict__ KVT,
                                                    float* __restrict__ PART)
{
  __shared__ __align__(16) short Qs[64 * 40];      // [q][d] d in [16,32) zero
  __shared__ __align__(16) short Ks[2][32 * 40];   // [key][d] d in [16,32) zero
  __shared__ __align__(16) short Vs[2][16 * 40];   // [d][key]
  __shared__ __align__(16) short Ps[4][16 * 40];   // per-wave [q][key]
  int s = blockIdx.x, h = blockIdx.y;
  int b = blockIdx.z >> 2, qb = blockIdx.z & 3;
  int tid = threadIdx.x;
  int w = tid >> 6, lane = tid & 63;
  int lane15 = lane & 15, lgrp = lane >> 4;
  const short* Kb = (const short*)KVT + ((long)b * 256 + h * 16) * HW;
  const short* Vb = Kb + (long)128 * HW;
  int nbeg = s * SPLITLEN;

  // zero the d=[16,32) pad of both K buffers (disjoint from staged d<16)
  for (int e = tid; e < 2 * 32 * 16; e += 256) {
    int buf = e >> 9, rr = e & 511;
    int kk = rr >> 4, d2 = rr & 15;
    Ks[buf][kk * 40 + 16 + d2] = 0;
  }
  // stage Q once: q = tid>>2 (0..63), dgroup = tid&3 -> short8 at [q][dg*8]
  {
    int q = tid >> 2, dg = tid & 3;
    int gq = qb * 64 + q;
    short8 v = {};
    if (dg < 2 && gq < PQ) {
      const float* qp = QH + ((long)(b * PQ + gq)) * HIDDEN + h * 16 + dg * 8;
#pragma unroll
      for (int j = 0; j < 8; j++) v[j] = f2bf_bits(qp[j] * 0.25f);
    }
    *(short8*)&Qs[q * 40 + dg * 8] = v;
  }

  auto stageKV = [&](int t, int buf) {
    int kb0 = nbeg + t * CHK;
    for (int e = tid; e < 512; e += 256) {
      int d = e >> 5, kk = e & 31;
      long gk = kb0 + kk; if (gk >= HW) gk = HW - 1;   // clamped; masked later
      long go = (long)d * HW + gk;
      Ks[buf][kk * 40 + d] = Kb[go];
      Vs[buf][d * 40 + kk] = Vb[go];
    }
  };

  stageKV(0, 0);
  __syncthreads();

  short8 aq = *(const short8*)&Qs[(w * 16 + lane15) * 40 + lgrp * 8];
  float m[4] = {-1e30f, -1e30f, -1e30f, -1e30f};
  float l[4] = {0.f, 0.f, 0.f, 0.f};
  f32x4 accO = {};
  const int NTL = (SPLITLEN + CHK - 1) / CHK;  // 23 (last chunk 16 valid)
  for (int t = 0; t < NTL; t++) {
    int cur = t & 1;
    if (t + 1 < NTL) stageKV(t + 1, cur ^ 1);
    int valid = SPLITLEN - t * CHK; if (valid > CHK) valid = CHK;
    short8 bk0 = *(const short8*)&Ks[cur][lane15 * 40 + lgrp * 8];
    short8 bk1 = *(const short8*)&Ks[cur][(16 + lane15) * 40 + lgrp * 8];
    f32x4 z = {};
    f32x4 s0 = __builtin_amdgcn_mfma_f32_16x16x32_bf16(aq, bk0, z, 0, 0, 0);
    f32x4 s1 = __builtin_amdgcn_mfma_f32_16x16x32_bf16(aq, bk1, z, 0, 0, 0);
    bool msk0 = (lane15 >= valid);
    bool msk1 = (16 + lane15 >= valid);
#pragma unroll
    for (int r = 0; r < 4; r++) {
      float x0 = msk0 ? -1e30f : s0[r];
      float x1 = msk1 ? -1e30f : s1[r];
      float mx = fmaxf(x0, x1);
      mx = fmaxf(mx, __shfl_xor(mx, 1, 64));
      mx = fmaxf(mx, __shfl_xor(mx, 2, 64));
      mx = fmaxf(mx, __shfl_xor(mx, 4, 64));
      mx = fmaxf(mx, __shfl_xor(mx, 8, 64));
      float mn = fmaxf(m[r], mx);
      float p0 = exp2f((x0 - mn) * L2E);
      float p1 = exp2f((x1 - mn) * L2E);
      float sum = p0 + p1;
      sum += __shfl_xor(sum, 1, 64);
      sum += __shfl_xor(sum, 2, 64);
      sum += __shfl_xor(sum, 4, 64);
      sum += __shfl_xor(sum, 8, 64);
      float al = exp2f((m[r] - mn) * L2E);
      l[r] = l[r] * al + sum;
      m[r] = mn;
      accO[r] *= al;
      Ps[w][(lgrp * 4 + r) * 40 + lane15] = f2bf_bits(p0);
      Ps[w][(lgrp * 4 + r) * 40 + 16 + lane15] = f2bf_bits(p1);
    }
    short8 ap = *(const short8*)&Ps[w][lane15 * 40 + lgrp * 8];
    short8 bv = *(const short8*)&Vs[cur][lane15 * 40 + lgrp * 8];
    accO = __builtin_amdgcn_mfma_f32_16x16x32_bf16(ap, bv, accO, 0, 0, 0);
    __syncthreads();
  }
  long base = ((((long)(b * 8 + h)) * NSPLIT + s) * PQ) * 18;
#pragma unroll
  for (int r = 0; r < 4; r++) {
    int gq = qb * 64 + w * 16 + lgrp * 4 + r;
    if (gq < PQ) {
      long ro = base + (long)gq * 18;
      PART[ro + lane15] = accO[r];
      if (lane15 == 0) { PART[ro + 16] = m[r]; PART[ro + 17] = l[r]; }
    }
  }
}

__global__ void combine_k(const float* __restrict__ PART, float* __restrict__ CAO)
{
  int t = blockIdx.x * 256 + threadIdx.x;
  if (t >= 2 * 8 * PQ * 16) return;
  int d = t & 15; int r = t >> 4;
  int q = r % PQ; r /= PQ;
  int h = r & 7; int b = r >> 3;
  long base = (((long)(b * 8 + h)) * NSPLIT) * PQ * 18 + (long)q * 18;
  float M = -1e30f;
  for (int s = 0; s < NSPLIT; s++) M = fmaxf(M, PART[base + (long)s * PQ * 18 + 16]);
  float L = 0.f, O = 0.f;
  for (int s = 0; s < NSPLIT; s++) {
    long p0 = base + (long)s * PQ * 18;
    float w = expf(PART[p0 + 16] - M);
    L += PART[p0 + 17] * w;
    O += PART[p0 + d] * w;
  }
  CAO[((long)(b * PQ + q)) * HIDDEN + h * 16 + d] = (L > 0.f) ? O / L : 0.f;
}

__global__ __launch_bounds__(256) void ln_k(const float* __restrict__ PRE,
                                            const float* __restrict__ g,
                                            const float* __restrict__ bta,
                                            float* __restrict__ X)
{
  int row = blockIdx.x * 4 + (threadIdx.x >> 6);
  int lane = threadIdx.x & 63;
  const float* p = PRE + (long)row * HIDDEN;
  float v0 = p[lane], v1 = p[lane + 64];
  float s = v0 + v1;
#pragma unroll
  for (int o = 32; o; o >>= 1) s += __shfl_xor(s, o, 64);
  float mu = s * (1.f / 128.f);
  float d0 = v0 - mu, d1 = v1 - mu;
  float vs = d0 * d0 + d1 * d1;
#pragma unroll
  for (int o = 32; o; o >>= 1) vs += __shfl_xor(vs, o, 64);
  float rs = rsqrtf(vs * (1.f / 128.f) + 1e-5f);
  float* xo = X + (long)row * HIDDEN;
  xo[lane] = d0 * rs * g[lane] + bta[lane];
  xo[lane + 64] = d1 * rs * g[lane + 64] + bta[lane + 64];
}

__global__ __launch_bounds__(128) void conv1d_k(const float* __restrict__ X,
                                                const float* __restrict__ w,
                                                const float* __restrict__ bias,
                                                const float* __restrict__ g,
                                                const float* __restrict__ beta,
                                                float* __restrict__ Y)
{
  int p = blockIdx.x, b = blockIdx.y;
  int co = threadIdx.x;
  __shared__ float xs[3][HIDDEN];
  for (int e = co; e < 3 * HIDDEN; e += HIDDEN) {
    int t = e >> 7, c = e & 127;
    int pp = p + t - 1;
    xs[t][c] = (pp >= 0 && pp < PQ) ? X[((long)(b * PQ + pp)) * HIDDEN + c] : 0.f;
  }
  __syncthreads();
  const float* wr = w + (long)co * HIDDEN * 3;
  float acc = 0.f;
  for (int c = 0; c < HIDDEN; c++) {
    acc = fmaf(xs[0][c], wr[c * 3 + 0], acc);
    acc = fmaf(xs[1][c], wr[c * 3 + 1], acc);
    acc = fmaf(xs[2][c], wr[c * 3 + 2], acc);
  }
  float v = (acc + bias[co]) * g[co] + beta[co];
  Y[((long)(b * PQ + p)) * HIDDEN + co] = fmaxf(v, 0.f);
}

__global__ void head2_k(const float* __restrict__ Y, const float* __restrict__ w,
                        const float* __restrict__ bias, const float* __restrict__ qpos,
                        float* __restrict__ OUT, int N, float* __restrict__ qnext)
{
  int t = blockIdx.x * 256 + threadIdx.x;
  if (t >= 2 * N * PQ) return;
  int p = t % PQ; int r = t / PQ; int co = r % N; int b = r / N;
  const float* wr = w + (long)co * HIDDEN * 3;
  float acc = 0.f;
  for (int tap = 0; tap < 3; tap++) {
    int pp = p + tap - 1;
    if (pp < 0 || pp >= PQ) continue;
    const float* yr = Y + ((long)(b * PQ + pp)) * HIDDEN;
    for (int c = 0; c < HIDDEN; c++)
      acc = fmaf(yr[c], wr[c * 3 + tap], acc);
  }
  float v = acc + bias[co];
  if (qpos) v += qpos[((long)(b * PQ + p)) * 2 + co];
  OUT[((long)(b * N + co)) * PQ + p] = v;
  if (qnext) qnext[((long)(b * PQ + p)) * 2 + co] = v;
}

__global__ void out_k(const float* __restrict__ CENT, const float* __restrict__ HMP,
                      void* __restrict__ out, const unsigned* __restrict__ FLAGS)
{
  int t = blockIdx.x * 256 + threadIdx.x;
  if (t >= 2 * 12 * PQ) return;
  int p = t % PQ; int r = t / PQ; int ch = r % 12; int b = r / 12;
  float v = (ch < 2) ? CENT[((long)(b * 2 + ch)) * PQ + p]
                     : HMP[((long)(b * 10 + ch - 2)) * PQ + p];
  if (FLAGS[0]) ((bf16*)out)[t] = __float2bfloat16(v);
  else          ((float*)out)[t] = v;
}

// ---------------------------------------------------------------------------
extern "C" void kernel_launch(void* const* d_in, const int* in_sizes, int n_in,
                              void* d_out, int out_size, void* d_ws, size_t ws_size,
                              hipStream_t stream)
{
  (void)n_in; (void)out_size; (void)ws_size;

  // ---- workspace layout (~80 MB == validated watermark) -------------------
  float* F = (float*)d_ws;
  size_t off = 0;
  int aoff[42];
  {
    size_t acc = 0;
    for (int i = 2; i < 42; i++) { aoff[i] = (int)acc; acc += (size_t)in_sizes[i]; }
    off = acc;
  }
  float* ARENA = F;
  float* LIDF = F + off;                        // [2][128][HW] fp32 (dead after gather)
  bf16*  KVT16 = (bf16*)(F + off);              // alias: [2][256][HW] bf16 (decoder)
  off += 8294400;
  // R17: HBUF2F spans the HBUF region AND the CAMF16 region (contiguous,
  // 8,294,400 floats = [2][128][HW] fp32). Legal because cam conv is MOVED
  // AFTER the heatmap/top-k phase — CAMF16 has no consumer before kvproj.
  float* HBUF2F = F + off;                      // [2][128][HW] fp32 (hm scratch)
  bf16*  HBUF2B = (bf16*)(F + off);             // alias: bf16 [2][128][HW] (bf16 mode)
  bf16*  KPET16 = (bf16*)(F + off);             // alias: [128][HW] bf16 (decoder)
  float* PART  = F + off;                       // alias: [2][8][NSPLIT][200][18]
  off += 4147200;
  bf16*  CAMF16 = (bf16*)(F + off);             // [2][128][HW] bf16 (decoder-only)
  off += 4147200;
  float* HEAT  = F + off;                       // [2][10][HW] (dead after nms)
  float* SCORE = F + off + 648000;              // (dead after collect)
  off += 1296000;
  float* X   = F + off; off += 51200;           // decoder smalls — all dead during
  float* XQ  = F + off; off += 51200;           // convs; WB_* aliases this region
  float* QPE = F + off; off += 51200;
  float* T1Q = F + off; off += 51200;
  float* SQKV = F + off; off += 153600;
  float* SAO = F + off; off += 51200;
  float* PRE = F + off; off += 51200;
  float* QH2 = F + off; off += 51200;
  float* CAO = F + off; off += 51200;
  float* FF1 = F + off; off += 102400;
  float* YC  = F + off; off += 51200;           // X..YC span = 716800 floats
  float* CENT = F + off; off += 800;
  float* HMP = F + off; off += 4000;
  float* QPA = F + off; off += 800;
  float* QPB = F + off; off += 800;
  unsigned* U = (unsigned*)(F + off);
  unsigned* HIST  = U;                          // [0, 8192)
  unsigned* ACNT  = U + 8192;                   // 2
  unsigned* THR   = U + 8194;                   // 2
  unsigned* FLAGS = U + 8196;                   // 2 (NOT zeroed by zero_u32)
  unsigned* TOPC  = U + 8198;                   // 400
  unsigned* TOPI  = U + 8598;                   // 400
  unsigned long long* CAND = (unsigned long long*)(U + 9000); // 2*CAP u64
  // 16-bit MFMA weight planes: alias the decoder-smalls region (dead during
  // wprep + convs). 1,327,104 shorts = 663,552 floats fits 716,800-float span.
  short* WB_LID = (short*)((((uintptr_t)X) + 15) & ~(uintptr_t)15);
  short* WB_CAM = WB_LID + 884736;              // 2*9*12*8*512 = 884736
  short* WB_HM1 = WB_CAM + 110592;              // 1*9*3*8*512  = 110592
  short* WB_HM2 = WB_HM1 + 294912;              // 2*9*4*8*512  = 294912 (+36864)

  auto W = [&](int i) -> const float* { return ARENA + aoff[i]; };

  // ---- dtype detect + weight conversion -----------------------------------
  detect_k<<<1, 256, 0, stream>>>((const unsigned*)d_in[0], FLAGS);
  {
    CvtArgs a;
    for (int i = 2; i < 42; i++) { a.src[i - 2] = d_in[i]; a.n[i - 2] = in_sizes[i]; a.off[i - 2] = aoff[i]; }
    cvt_k<<<dim3(432, 40), 256, 0, stream>>>(a, ARENA, FLAGS);
  }
  wprep_k<<<3456, 256, 0, stream>>>(W(2), WB_LID, 128, 384, 12, 8, 1, FLAGS, 1);
  wprep_k<<<432, 256, 0, stream>>>(W(4), WB_CAM, 128, 80, 3, 8, 0, FLAGS, 1);
  wprep_k<<<1152, 256, 0, stream>>>(W(6), WB_HM1, 128, 128, 4, 8, 1, FLAGS, 1);
  wprep_k<<<144, 256, 0, stream>>>(W(10), WB_HM2, 10, 128, 4, 1, 1, FLAGS, 1);

  auto gemm = [&](const float* A, const float* A2, int lda, const float* Wp,
                  const float* bias, int act, const float* res, float* C, int ldc,
                  int M, int N, int K) {
    dim3 grid((M + 63) / 64, (N + 63) / 64, 1);
    gemm_k<float, float><<<grid, 256, 0, stream>>>(
        A, A2, lda, 0, 0L, Wp, bias, act, res,
        nullptr, nullptr, nullptr, nullptr, C, ldc, 0, 0L, M, N, K);
  };

  // ---- lidar conv + heatmap path (cam conv DEFERRED past top-k) -----------
  conv_mfma<1, 1, 4, 4, 2, 60, float><<<dim3(544, 1, 2), 256, 0, stream>>>(
      d_in[0], FLAGS, 1, 1, (long)384 * HW, WB_LID, W(3), nullptr, nullptr, 0,
      LIDF, (long)128 * HW, 128, 384, 12, 8);
  conv_mfma<3, 1, 4, 4, 2, 60, float><<<dim3(544, 1, 2), 256, 0, stream>>>(
      d_in[0], FLAGS, 1, 0, (long)384 * HW, WB_LID, W(3), nullptr, nullptr, 0,
      LIDF, (long)128 * HW, 128, 384, 12, 8);
  // hm1/hm2 merged across batches (z=2, 1088 blocks) in BOTH modes.
  // fp32 mode: exact fp16-split, fp32 h in HBUF2F (HBUF+CAMF16 regions).
  conv_mfma<3, 1, 4, 4, 2, 60, float><<<dim3(544, 1, 2), 256, 0, stream>>>(
      LIDF, FLAGS, 0, 0, (long)128 * HW, WB_HM1, W(7), W(8), W(9), 1,
      HBUF2F, (long)128 * HW, 128, 128, 4, 8);
  conv_mfma<3, 4, 1, 1, 1, 60, float><<<dim3(544, 1, 2), 256, 0, stream>>>(
      HBUF2F, FLAGS, 0, 0, (long)128 * HW, WB_HM2, W(11), nullptr, nullptr, 2,
      HEAT, (long)NCLS * HW, 10, 128, 4, 1);
  // bf16 mode: bf16 round (matches reference's own bf16 tensors), bf16 h.
  conv_mfma<2, 1, 4, 4, 2, 60, bf16><<<dim3(544, 1, 2), 256, 0, stream>>>(
      LIDF, FLAGS, 0, 1, (long)128 * HW, WB_HM1, W(7), W(8), W(9), 1,
      HBUF2B, (long)128 * HW, 128, 128, 4, 8);
  conv_mfma<1, 4, 1, 1, 1, 60, float><<<dim3(544, 1, 2), 256, 0, stream>>>(
      HBUF2B, FLAGS, 0, 1, (long)128 * HW, WB_HM2, W(11), nullptr, nullptr, 2,
      HEAT, (long)NCLS * HW, 10, 128, 4, 1);

  // ---- NMS + exact top-200 ------------------------------------------------
  nms_k<<<(2 * NCLS * HW + 255) / 256, 256, 0, stream>>>(HEAT, SCORE);
  zero_u32<<<(8196 + 255) / 256, 256, 0, stream>>>(U, 8196);
  hist_k<<<dim3(240, 2), 256, 0, stream>>>(SCORE, HIST);
  thresh_k<<<2, 256, 0, stream>>>(HIST, THR);
  collect_k<<<(2 * NCLS * HW + 255) / 256, 256, 0, stream>>>(SCORE, THR, ACNT, CAND);
  select_k<<<2, 64, 0, stream>>>(CAND, ACNT, TOPC, TOPI, QPA);
  gather_k<<<200, 256, 0, stream>>>(LIDF, TOPC, TOPI, W(12), W(13), X);

  // ---- cam conv (deferred; overwrites hm scratch upper half) --------------
  conv_mfma<1, 1, 4, 4, 2, 60, bf16><<<dim3(544, 1, 2), 256, 0, stream>>>(
      d_in[1], FLAGS, 1, 1, (long)80 * HW, WB_CAM, W(5), nullptr, nullptr, 0,
      CAMF16, (long)128 * HW, 128, 80, 3, 8);
  conv_mfma<0, 1, 4, 4, 2, 60, bf16><<<dim3(544, 1, 2), 256, 0, stream>>>(
      d_in[1], FLAGS, 1, 0, (long)80 * HW, WB_CAM, W(5), nullptr, nullptr, 0,
      CAMF16, (long)128 * HW, 128, 80, 3, 8);

  // ---- decoder layers -----------------------------------------------------
  for (int i = 0; i < 2; i++) {
    const float* qcur = (i == 0) ? QPA : QPB;
    float* qnext = (i == 0) ? QPB : QPA;
    // query pos-embed fused into GEMM staging (amode 3, A = qpos)
    gemm_k<float, float><<<dim3(7, 2, 1), 256, 0, stream>>>(
        qcur, (const float*)nullptr, 0, 3, 0L,
        W(18) + (size_t)(i * 2 + 0) * 16384, W(19) + (i * 2 + 0) * 128, 0, nullptr,
        W(14) + (i * 2 + 0) * 256, W(15) + (i * 2 + 0) * 128,
        W(16) + (i * 2 + 0) * 128, W(17) + (i * 2 + 0) * 128,
        QPE, 128, 0, 0L, 400, 128, 128);
    // key pos-embed (BEV grid fused), bf16 MFMA, stored transposed [128][HW]
    kpe_mfma_k<<<dim3(507, 2), 256, 0, stream>>>(
        W(14) + (i * 2 + 1) * 256, W(15) + (i * 2 + 1) * 128,
        W(16) + (i * 2 + 1) * 128, W(17) + (i * 2 + 1) * 128,
        W(18) + (size_t)(i * 2 + 1) * 16384, W(19) + (i * 2 + 1) * 128,
        KPET16);
    // self-attention (X+QPE fused via A2)
    gemm(X, QPE, 128, W(20) + (size_t)(i * 2 + 0) * 49152, W(21) + (i * 2 + 0) * 384,
         0, nullptr, SQKV, 384, 400, 384, 128);
    self_attn_k<<<dim3(200, 8, 2), 64, 0, stream>>>(SQKV, SAO);
    gemm(SAO, nullptr, 128, W(22) + (size_t)(i * 2 + 0) * 16384, W(23) + (i * 2 + 0) * 128,
         0, X, PRE, 128, 400, 128, 128);
    ln_k<<<100, 256, 0, stream>>>(PRE, W(24) + (i * 3 + 0) * 128, W(25) + (i * 3 + 0) * 128, X);
    // cross-attention Q projection (X+QPE fused via A2) — N=128 (Q rows only)
    gemm(X, QPE, 128, W(20) + (size_t)(i * 2 + 1) * 49152, W(21) + (i * 2 + 1) * 384,
         0, nullptr, QH2, 128, 400, 128, 128);
    kvproj_k<<<dim3(507, 2, 2), 256, 0, stream>>>(
        CAMF16, KPET16,
        W(20) + (size_t)(i * 2 + 1) * 49152 + 16384,
        W(21) + (i * 2 + 1) * 384 + 128, KVT16);
    flash_mfma_k<<<dim3(NSPLIT, 8, 8), 256, 0, stream>>>(QH2, KVT16, PART);
    combine_k<<<200, 256, 0, stream>>>(PART, CAO);
    gemm(CAO, nullptr, 128, W(22) + (size_t)(i * 2 + 1) * 16384, W(23) + (i * 2 + 1) * 128,
         0, X, PRE, 128, 400, 128, 128);
    ln_k<<<100, 256, 0, stream>>>(PRE, W(24) + (i * 3 + 1) * 128, W(25) + (i * 3 + 1) * 128, X);
    // FFN
    gemm(X, nullptr, 128, W(26) + (size_t)i * 32768, W(27) + i * 256,
         1, nullptr, FF1, 256, 400, 256, 128);
    gemm(FF1, nullptr, 256, W(28) + (size_t)i * 32768, W(29) + i * 128,
         0, X, PRE, 128, 400, 128, 256);
    ln_k<<<100, 256, 0, stream>>>(PRE, W(24) + (i * 3 + 2) * 128, W(25) + (i * 3 + 2) * 128, X);
    // prediction heads
    conv1d_k<<<dim3(200, 2), 128, 0, stream>>>(X, W(30) + (size_t)i * 49152,
        W(31) + i * 128, W(32) + i * 128, W(33) + i * 128, YC);
    head2_k<<<4, 256, 0, stream>>>(YC, W(34) + (size_t)i * 768, W(35) + i * 2,
        qcur, CENT, 2, qnext);
    conv1d_k<<<dim3(200, 2), 128, 0, stream>>>(X, W(36) + (size_t)i * 49152,
        W(37) + i * 128, W(38) + i * 128, W(39) + i * 128, YC);
    head2_k<<<16, 256, 0, stream>>>(YC, W(40) + (size_t)i * 3840, W(41) + i * 10,
        nullptr, HMP, 10, nullptr);
  }
  out_k<<<19, 256, 0, stream>>>(CENT, HMP, d_out, FLAGS);
}